// Round 4
// baseline (291.124 us; speedup 1.0000x reference)
//
#include <hip/hip_runtime.h>
#include <math.h>

#define N_NODES 10000
#define N_EDGES 320000
#define IN_FEATS 256
#define N_HEADS 4
#define N_UNITS 64
#define OUT_FEATS 47
#define NEG_SLOPE 0.2f

__device__ __forceinline__ float wave_reduce_sum(float v) {
#pragma unroll
  for (int s = 32; s > 0; s >>= 1) v += __shfl_down(v, s, 64);
  return __shfl(v, 0, 64);
}
__device__ __forceinline__ float wave_reduce_max(float v) {
#pragma unroll
  for (int s = 32; s > 0; s >>= 1) v = fmaxf(v, __shfl_down(v, s, 64));
  return __shfl(v, 0, 64);
}

__device__ __forceinline__ float lrelu_exp(float s) {
  s = (s > 0.f) ? s : NEG_SLOPE * s;
  return expf(s);
}

// fp32 -> bf16 with round-to-nearest-even
__device__ __forceinline__ unsigned f2bf(float f) {
  unsigned u = __float_as_uint(f);
  return (u + 0x7FFFu + ((u >> 16) & 1u)) >> 16;
}

// ---------------- CSR build ----------------
__global__ void count_deg_kernel(const int* __restrict__ dst, int* __restrict__ deg) {
  int e = blockIdx.x * blockDim.x + threadIdx.x;
  if (e < N_EDGES) atomicAdd(&deg[dst[e]], 1);
}

__global__ void scan_offsets_kernel(const int* __restrict__ deg, int* __restrict__ offsets,
                                    int* __restrict__ cursor) {
  __shared__ int partial[256];
  int t = threadIdx.x;
  const int chunk = (N_NODES + 255) / 256;  // 40
  int start = t * chunk;
  int end = min(start + chunk, N_NODES);
  int sum = 0;
  for (int i = start; i < end; ++i) sum += deg[i];
  partial[t] = sum;
  __syncthreads();
  for (int s = 1; s < 256; s <<= 1) {
    int v = (t >= s) ? partial[t - s] : 0;
    __syncthreads();
    partial[t] += v;
    __syncthreads();
  }
  int base = (t == 0) ? 0 : partial[t - 1];
  for (int i = start; i < end; ++i) {
    offsets[i] = base;
    cursor[i] = base;
    base += deg[i];
  }
  if (t == 0) offsets[N_NODES] = partial[255];
}

// CSR fill: src_csr[p] = source node of p-th incoming edge (dst-bucketed).
__global__ void fill_csr_kernel(const int* __restrict__ src, const int* __restrict__ dst,
                                int* __restrict__ cursor, int* __restrict__ src_csr) {
  int e = blockIdx.x * blockDim.x + threadIdx.x;
  if (e < N_EDGES) {
    int p = atomicAdd(&cursor[dst[e]], 1);
    src_csr[p] = src[e];
  }
}

// ---------------- Layer 1 GEMM: feat1h(bf16) = features @ W1, fused el1/er1 ----------------
// 16 rows x 256 cols per block; thread = 4x4 register tile. Feature LDS reads
// are wave-uniform broadcasts; W1 staged in 16-k LDS slices.
__global__ __launch_bounds__(256) void gemm1_kernel(
    const float* __restrict__ features, const float* __restrict__ W1,
    const float* __restrict__ al1, const float* __restrict__ ar1,
    unsigned short* __restrict__ feat1h, float* __restrict__ el1, float* __restrict__ er1) {
  __shared__ float ldsf[16 * 256];
  __shared__ float ldsw[16 * 256];
  int t = threadIdx.x;
  int n0 = blockIdx.x * 16;
  int lane = t & 63;
  int r0 = (t >> 6) * 4;
  int c = lane * 4;

  const float4* srcf4 = (const float4*)(features + (size_t)n0 * 256);
  float4* f4 = (float4*)ldsf;
#pragma unroll
  for (int i = 0; i < 4; ++i) f4[t + i * 256] = srcf4[t + i * 256];

  float4 acc[4];
#pragma unroll
  for (int i = 0; i < 4; ++i) acc[i] = make_float4(0.f, 0.f, 0.f, 0.f);

  for (int k0 = 0; k0 < 256; k0 += 16) {
    __syncthreads();
    const float4* w4 = (const float4*)(W1 + (size_t)k0 * 256);
    float4* lw4 = (float4*)ldsw;
#pragma unroll
    for (int i = 0; i < 4; ++i) lw4[t + i * 256] = w4[t + i * 256];
    __syncthreads();

#pragma unroll
    for (int kk = 0; kk < 16; kk += 4) {
      float4 fv[4];
#pragma unroll
      for (int i = 0; i < 4; ++i)
        fv[i] = *(const float4*)&ldsf[(r0 + i) * 256 + k0 + kk];  // broadcast
      float4 wv[4];
#pragma unroll
      for (int j = 0; j < 4; ++j) wv[j] = *(const float4*)&ldsw[(kk + j) * 256 + c];
#pragma unroll
      for (int i = 0; i < 4; ++i) {
        acc[i].x += fv[i].x * wv[0].x + fv[i].y * wv[1].x + fv[i].z * wv[2].x + fv[i].w * wv[3].x;
        acc[i].y += fv[i].x * wv[0].y + fv[i].y * wv[1].y + fv[i].z * wv[2].y + fv[i].w * wv[3].y;
        acc[i].z += fv[i].x * wv[0].z + fv[i].y * wv[1].z + fv[i].z * wv[2].z + fv[i].w * wv[3].z;
        acc[i].w += fv[i].x * wv[0].w + fv[i].y * wv[1].w + fv[i].z * wv[2].w + fv[i].w * wv[3].w;
      }
    }
  }

  float4 alv = ((const float4*)al1)[lane];
  float4 arv = ((const float4*)ar1)[lane];
#pragma unroll
  for (int i = 0; i < 4; ++i) {
    int row = n0 + r0 + i;
    unsigned p0 = f2bf(acc[i].x) | (f2bf(acc[i].y) << 16);
    unsigned p1 = f2bf(acc[i].z) | (f2bf(acc[i].w) << 16);
    *(uint2*)&feat1h[(size_t)row * 256 + c] = make_uint2(p0, p1);
    float el = acc[i].x * alv.x + acc[i].y * alv.y + acc[i].z * alv.z + acc[i].w * alv.w;
    float er = acc[i].x * arv.x + acc[i].y * arv.y + acc[i].z * arv.z + acc[i].w * arv.w;
#pragma unroll
    for (int s = 8; s > 0; s >>= 1) {
      el += __shfl_down(el, s, 16);
      er += __shfl_down(er, s, 16);
    }
    if ((lane & 15) == 0) {
      el1[row * 4 + (lane >> 4)] = el;
      er1[row * 4 + (lane >> 4)] = er;
    }
  }
}

// ---------------- Layer 1 aggregate: bf16 gather, in-kernel scores ----------------
// Wave w: edges w, w+4, ...; lane covers dims 4*lane..4*lane+3 (head=lane>>4).
__global__ __launch_bounds__(256) void agg1_kernel(
    const int* __restrict__ src_csr, const int* __restrict__ offsets,
    const unsigned short* __restrict__ feat1h, const float* __restrict__ el1,
    const float* __restrict__ er1, float* __restrict__ h2) {
  __shared__ float ldsacc[4][256];
  __shared__ float ldssum[4][4];
  int n = blockIdx.x;
  int w = threadIdx.x >> 6;
  int lane = threadIdx.x & 63;
  int off = offsets[n];
  int deg = offsets[n + 1] - off;
  int hsel = lane >> 4;
  float4 er4 = ((const float4*)er1)[n];

  float4 acc = {0.f, 0.f, 0.f, 0.f};
  float4 esum = {0.f, 0.f, 0.f, 0.f};

  for (int j = w; j < deg; j += 4) {
    int sn = src_csr[off + j];
    float4 el4 = ((const float4*)el1)[sn];  // broadcast, cache-resident
    uint2 u = *(const uint2*)&feat1h[(size_t)sn * 256 + lane * 4];
    float a0 = lrelu_exp(el4.x + er4.x);
    float a1 = lrelu_exp(el4.y + er4.y);
    float a2 = lrelu_exp(el4.z + er4.z);
    float a3 = lrelu_exp(el4.w + er4.w);
    float f0 = __uint_as_float(u.x << 16);
    float f1 = __uint_as_float(u.x & 0xFFFF0000u);
    float f2 = __uint_as_float(u.y << 16);
    float f3 = __uint_as_float(u.y & 0xFFFF0000u);
    float aw = (hsel == 0) ? a0 : (hsel == 1) ? a1 : (hsel == 2) ? a2 : a3;
    acc.x += aw * f0;
    acc.y += aw * f1;
    acc.z += aw * f2;
    acc.w += aw * f3;
    esum.x += a0;
    esum.y += a1;
    esum.z += a2;
    esum.w += a3;
  }
  *(float4*)&ldsacc[w][lane * 4] = acc;
  if (lane == 0) *(float4*)&ldssum[w][0] = esum;
  __syncthreads();

  int t = threadIdx.x;
  float tot = ldsacc[0][t] + ldsacc[1][t] + ldsacc[2][t] + ldsacc[3][t];
  int h = t >> 6;
  float denom = ldssum[0][h] + ldssum[1][h] + ldssum[2][h] + ldssum[3][h];
  float val = tot / fmaxf(denom, 1e-9f);
  h2[(size_t)n * 256 + t] = (val > 0.f) ? val : expm1f(val);
}

// ---------------- Layer 2 GEMM: feat2 = h2 @ W2, fused el2/er2 ----------------
__global__ __launch_bounds__(64) void gemm2_kernel(
    const float* __restrict__ h2, const float* __restrict__ W2,
    const float* __restrict__ al2, const float* __restrict__ ar2,
    float* __restrict__ feat2, float* __restrict__ el2, float* __restrict__ er2) {
  int n = blockIdx.x;
  int c = threadIdx.x;
  const float* hrow = h2 + (size_t)n * 256;
  float acc = 0.f;
  if (c < OUT_FEATS) {
    for (int k = 0; k < 256; k += 4) {
      float4 hv = *(const float4*)&hrow[k];
      acc += hv.x * W2[(k + 0) * OUT_FEATS + c] + hv.y * W2[(k + 1) * OUT_FEATS + c] +
             hv.z * W2[(k + 2) * OUT_FEATS + c] + hv.w * W2[(k + 3) * OUT_FEATS + c];
    }
    feat2[n * OUT_FEATS + c] = acc;
  }
  float el = (c < OUT_FEATS) ? acc * al2[c] : 0.f;
  float er = (c < OUT_FEATS) ? acc * ar2[c] : 0.f;
#pragma unroll
  for (int s = 32; s > 0; s >>= 1) {
    el += __shfl_down(el, s, 64);
    er += __shfl_down(er, s, 64);
  }
  if (c == 0) {
    el2[n] = el;
    er2[n] = er;
  }
}

// ---------------- Layer 2 aggregate + log_softmax, in-kernel scores ----------------
__global__ __launch_bounds__(256) void agg2_kernel(
    const int* __restrict__ src_csr, const int* __restrict__ offsets,
    const float* __restrict__ feat2, const float* __restrict__ el2,
    const float* __restrict__ er2, float* __restrict__ out) {
  __shared__ float ldsacc[4][48];
  __shared__ float ldssum[4];
  int n = blockIdx.x;
  int w = threadIdx.x >> 6;
  int lane = threadIdx.x & 63;
  int off = offsets[n];
  int deg = offsets[n + 1] - off;
  float ern = er2[n];

  float acc = 0.f;
  float esum = 0.f;
  for (int j = w; j < deg; j += 4) {
    int sn = src_csr[off + j];
    float a = lrelu_exp(el2[sn] + ern);  // broadcast, cache-resident
    float f = (lane < OUT_FEATS) ? feat2[(size_t)sn * OUT_FEATS + lane] : 0.f;
    acc += a * f;
    esum += a;
  }
  if (lane < OUT_FEATS) ldsacc[w][lane] = acc;
  if (lane == 0) ldssum[w] = esum;
  __syncthreads();

  if (threadIdx.x < 64) {
    int t = threadIdx.x;
    float denom = ldssum[0] + ldssum[1] + ldssum[2] + ldssum[3];
    float inv = 1.f / fmaxf(denom, 1e-9f);
    float logits = 0.f;
    if (t < OUT_FEATS)
      logits = (ldsacc[0][t] + ldsacc[1][t] + ldsacc[2][t] + ldsacc[3][t]) * inv;
    float v = (t < OUT_FEATS) ? logits : -INFINITY;
    float mx = wave_reduce_max(v);
    float ex = (t < OUT_FEATS) ? expf(logits - mx) : 0.f;
    float s = wave_reduce_sum(ex);
    if (t < OUT_FEATS) out[n * OUT_FEATS + t] = logits - mx - logf(s);
  }
}

extern "C" void kernel_launch(void* const* d_in, const int* in_sizes, int n_in,
                              void* d_out, int out_size, void* d_ws, size_t ws_size,
                              hipStream_t stream) {
  const float* features = (const float*)d_in[0];
  const int* src = (const int*)d_in[1];
  const int* dst = (const int*)d_in[2];
  const float* W1 = (const float*)d_in[3];
  const float* al1 = (const float*)d_in[4];
  const float* ar1 = (const float*)d_in[5];
  const float* W2 = (const float*)d_in[6];
  const float* al2 = (const float*)d_in[7];
  const float* ar2 = (const float*)d_in[8];
  float* out = (float*)d_out;

  char* ws = (char*)d_ws;
  size_t o = 0;
  auto alloc = [&](size_t bytes) {
    void* p = ws + o;
    o = (o + bytes + 255) & ~(size_t)255;
    return p;
  };
  unsigned short* feat1h = (unsigned short*)alloc((size_t)N_NODES * 256 * 2);
  float* h2 = (float*)alloc((size_t)N_NODES * 256 * 4);
  float* el1 = (float*)alloc((size_t)N_NODES * 4 * 4);
  float* er1 = (float*)alloc((size_t)N_NODES * 4 * 4);
  float* feat2 = (float*)alloc((size_t)N_NODES * OUT_FEATS * 4);
  float* el2v = (float*)alloc((size_t)N_NODES * 4);
  float* er2v = (float*)alloc((size_t)N_NODES * 4);
  int* deg = (int*)alloc((size_t)N_NODES * 4);
  int* cursor = (int*)alloc((size_t)N_NODES * 4);
  int* offsets = (int*)alloc((size_t)(N_NODES + 1) * 4);
  int* src_csr = (int*)alloc((size_t)N_EDGES * 4);

  hipMemsetAsync(deg, 0, (size_t)N_NODES * 4, stream);

  count_deg_kernel<<<(N_EDGES + 255) / 256, 256, 0, stream>>>(dst, deg);
  scan_offsets_kernel<<<1, 256, 0, stream>>>(deg, offsets, cursor);
  gemm1_kernel<<<N_NODES / 16, 256, 0, stream>>>(features, W1, al1, ar1, feat1h, el1, er1);
  fill_csr_kernel<<<(N_EDGES + 255) / 256, 256, 0, stream>>>(src, dst, cursor, src_csr);
  agg1_kernel<<<N_NODES, 256, 0, stream>>>(src_csr, offsets, feat1h, el1, er1, h2);
  gemm2_kernel<<<N_NODES, 64, 0, stream>>>(h2, W2, al2, ar2, feat2, el2v, er2v);
  agg2_kernel<<<N_NODES, 256, 0, stream>>>(src_csr, offsets, feat2, el2v, er2v, out);
}

// Round 5
// 277.712 us; speedup vs baseline: 1.0483x; 1.0483x over previous
//
#include <hip/hip_runtime.h>
#include <math.h>

#define N_NODES 10000
#define N_EDGES 320000
#define IN_FEATS 256
#define N_HEADS 4
#define N_UNITS 64
#define OUT_FEATS 47
#define NEG_SLOPE 0.2f

__device__ __forceinline__ float wave_reduce_sum(float v) {
#pragma unroll
  for (int s = 32; s > 0; s >>= 1) v += __shfl_down(v, s, 64);
  return __shfl(v, 0, 64);
}
__device__ __forceinline__ float wave_reduce_max(float v) {
#pragma unroll
  for (int s = 32; s > 0; s >>= 1) v = fmaxf(v, __shfl_down(v, s, 64));
  return __shfl(v, 0, 64);
}

__device__ __forceinline__ float lrelu_exp(float s) {
  s = (s > 0.f) ? s : NEG_SLOPE * s;
  return expf(s);
}

// fp32 -> bf16 round-to-nearest-even
__device__ __forceinline__ unsigned f2bf(float f) {
  unsigned u = __float_as_uint(f);
  return (u + 0x7FFFu + ((u >> 16) & 1u)) >> 16;
}

// ---------------- CSR build ----------------
__global__ void count_deg_kernel(const int* __restrict__ dst, int* __restrict__ deg) {
  int e = blockIdx.x * blockDim.x + threadIdx.x;
  if (e < N_EDGES) atomicAdd(&deg[dst[e]], 1);
}

__global__ void scan_offsets_kernel(const int* __restrict__ deg, int* __restrict__ offsets,
                                    int* __restrict__ cursor) {
  __shared__ int partial[256];
  int t = threadIdx.x;
  const int chunk = (N_NODES + 255) / 256;  // 40
  int start = t * chunk;
  int end = min(start + chunk, N_NODES);
  int sum = 0;
  for (int i = start; i < end; ++i) sum += deg[i];
  partial[t] = sum;
  __syncthreads();
  for (int s = 1; s < 256; s <<= 1) {
    int v = (t >= s) ? partial[t - s] : 0;
    __syncthreads();
    partial[t] += v;
    __syncthreads();
  }
  int base = (t == 0) ? 0 : partial[t - 1];
  for (int i = start; i < end; ++i) {
    offsets[i] = base;
    cursor[i] = base;
    base += deg[i];
  }
  if (t == 0) offsets[N_NODES] = partial[255];
}

// CSR fill + layer-1 edge exp-scores, written CSR-ordered (no eidx needed).
// Softmax shift-invariance: |s| small with this data, exp(s) without
// max-subtraction is safe and matches reference within fp rounding.
__global__ void fill_escore1_kernel(const int* __restrict__ src, const int* __restrict__ dst,
                                    int* __restrict__ cursor, int* __restrict__ src_csr,
                                    const float* __restrict__ el1, const float* __restrict__ er1,
                                    float* __restrict__ escore1_csr) {
  int e = blockIdx.x * blockDim.x + threadIdx.x;
  if (e >= N_EDGES) return;
  int d = dst[e];
  int sn = src[e];
  int p = atomicAdd(&cursor[d], 1);
  src_csr[p] = sn;
  float4 el = ((const float4*)el1)[sn];
  float4 er = ((const float4*)er1)[d];
  float4 sc;
  sc.x = lrelu_exp(el.x + er.x);
  sc.y = lrelu_exp(el.y + er.y);
  sc.z = lrelu_exp(el.z + er.z);
  sc.w = lrelu_exp(el.w + er.w);
  ((float4*)escore1_csr)[p] = sc;
}

// ---------------- Layer 1 GEMM: feat1h(bf16) = features @ W1, fused el1/er1 ----------------
__global__ __launch_bounds__(256) void gemm1_kernel(
    const float* __restrict__ features, const float* __restrict__ W1,
    const float* __restrict__ al1, const float* __restrict__ ar1,
    unsigned short* __restrict__ feat1h, float* __restrict__ el1, float* __restrict__ er1) {
  __shared__ float ldsf[16 * 256];
  __shared__ float ldsw[16 * 256];
  int t = threadIdx.x;
  int n0 = blockIdx.x * 16;
  int lane = t & 63;
  int r0 = (t >> 6) * 4;
  int c = lane * 4;

  const float4* srcf4 = (const float4*)(features + (size_t)n0 * 256);
  float4* f4 = (float4*)ldsf;
#pragma unroll
  for (int i = 0; i < 4; ++i) f4[t + i * 256] = srcf4[t + i * 256];

  float4 acc[4];
#pragma unroll
  for (int i = 0; i < 4; ++i) acc[i] = make_float4(0.f, 0.f, 0.f, 0.f);

  for (int k0 = 0; k0 < 256; k0 += 16) {
    __syncthreads();
    const float4* w4 = (const float4*)(W1 + (size_t)k0 * 256);
    float4* lw4 = (float4*)ldsw;
#pragma unroll
    for (int i = 0; i < 4; ++i) lw4[t + i * 256] = w4[t + i * 256];
    __syncthreads();

#pragma unroll
    for (int kk = 0; kk < 16; kk += 4) {
      float4 fv[4];
#pragma unroll
      for (int i = 0; i < 4; ++i)
        fv[i] = *(const float4*)&ldsf[(r0 + i) * 256 + k0 + kk];  // broadcast
      float4 wv[4];
#pragma unroll
      for (int j = 0; j < 4; ++j) wv[j] = *(const float4*)&ldsw[(kk + j) * 256 + c];
#pragma unroll
      for (int i = 0; i < 4; ++i) {
        acc[i].x += fv[i].x * wv[0].x + fv[i].y * wv[1].x + fv[i].z * wv[2].x + fv[i].w * wv[3].x;
        acc[i].y += fv[i].x * wv[0].y + fv[i].y * wv[1].y + fv[i].z * wv[2].y + fv[i].w * wv[3].y;
        acc[i].z += fv[i].x * wv[0].z + fv[i].y * wv[1].z + fv[i].z * wv[2].z + fv[i].w * wv[3].z;
        acc[i].w += fv[i].x * wv[0].w + fv[i].y * wv[1].w + fv[i].z * wv[2].w + fv[i].w * wv[3].w;
      }
    }
  }

  float4 alv = ((const float4*)al1)[lane];
  float4 arv = ((const float4*)ar1)[lane];
#pragma unroll
  for (int i = 0; i < 4; ++i) {
    int row = n0 + r0 + i;
    unsigned p0 = f2bf(acc[i].x) | (f2bf(acc[i].y) << 16);
    unsigned p1 = f2bf(acc[i].z) | (f2bf(acc[i].w) << 16);
    *(uint2*)&feat1h[(size_t)row * 256 + c] = make_uint2(p0, p1);
    float el = acc[i].x * alv.x + acc[i].y * alv.y + acc[i].z * alv.z + acc[i].w * alv.w;
    float er = acc[i].x * arv.x + acc[i].y * arv.y + acc[i].z * arv.z + acc[i].w * arv.w;
#pragma unroll
    for (int s = 8; s > 0; s >>= 1) {
      el += __shfl_down(el, s, 16);
      er += __shfl_down(er, s, 16);
    }
    if ((lane & 15) == 0) {
      el1[row * 4 + (lane >> 4)] = el;
      er1[row * 4 + (lane >> 4)] = er;
    }
  }
}

// ---------------- Layer 1 aggregate: bf16 gather + precomputed escores ----------------
__global__ __launch_bounds__(256) void agg1_kernel(
    const int* __restrict__ src_csr, const int* __restrict__ offsets,
    const unsigned short* __restrict__ feat1h, const float* __restrict__ escore1_csr,
    float* __restrict__ h2) {
  __shared__ float ldsacc[4][256];
  __shared__ float ldssum[4][4];
  int n = blockIdx.x;
  int w = threadIdx.x >> 6;
  int lane = threadIdx.x & 63;
  int off = offsets[n];
  int deg = offsets[n + 1] - off;
  int hsel = lane >> 4;

  float4 acc = {0.f, 0.f, 0.f, 0.f};
  float4 esum = {0.f, 0.f, 0.f, 0.f};

  for (int j = w; j < deg; j += 4) {
    int sn = src_csr[off + j];                            // wave-uniform broadcast
    float4 a4 = ((const float4*)escore1_csr)[off + j];    // wave-uniform broadcast
    uint2 u = *(const uint2*)&feat1h[(size_t)sn * 256 + lane * 4];  // 512B coalesced
    float f0 = __uint_as_float(u.x << 16);
    float f1 = __uint_as_float(u.x & 0xFFFF0000u);
    float f2 = __uint_as_float(u.y << 16);
    float f3 = __uint_as_float(u.y & 0xFFFF0000u);
    float aw = (hsel == 0) ? a4.x : (hsel == 1) ? a4.y : (hsel == 2) ? a4.z : a4.w;
    acc.x += aw * f0;
    acc.y += aw * f1;
    acc.z += aw * f2;
    acc.w += aw * f3;
    esum.x += a4.x;
    esum.y += a4.y;
    esum.z += a4.z;
    esum.w += a4.w;
  }
  *(float4*)&ldsacc[w][lane * 4] = acc;
  if (lane == 0) *(float4*)&ldssum[w][0] = esum;
  __syncthreads();

  int t = threadIdx.x;
  float tot = ldsacc[0][t] + ldsacc[1][t] + ldsacc[2][t] + ldsacc[3][t];
  int h = t >> 6;
  float denom = ldssum[0][h] + ldssum[1][h] + ldssum[2][h] + ldssum[3][h];
  float val = tot / fmaxf(denom, 1e-9f);
  h2[(size_t)n * 256 + t] = (val > 0.f) ? val : expm1f(val);
}

// ---------------- Layer 2 GEMM: feat2 = h2 @ W2 (16 nodes/block), fused el2/er2 ----------------
// Thread t: rows r0..r0+3 (r0=(t>>6)*4), col c=t&63 (active c<47).
__global__ __launch_bounds__(256) void gemm2_kernel(
    const float* __restrict__ h2, const float* __restrict__ W2,
    const float* __restrict__ al2, const float* __restrict__ ar2,
    float* __restrict__ feat2, float* __restrict__ el2, float* __restrict__ er2) {
  __shared__ float ldsh[16 * 256];
  __shared__ float ldsw[16 * OUT_FEATS];
  int t = threadIdx.x;
  int n0 = blockIdx.x * 16;
  int lane = t & 63;
  int r0 = (t >> 6) * 4;
  int c = lane;
  int cs = (c < OUT_FEATS) ? c : (OUT_FEATS - 1);  // clamp to avoid LDS OOB/NaN

  const float4* srch4 = (const float4*)(h2 + (size_t)n0 * 256);
  float4* h4 = (float4*)ldsh;
#pragma unroll
  for (int i = 0; i < 4; ++i) h4[t + i * 256] = srch4[t + i * 256];

  float acc[4] = {0.f, 0.f, 0.f, 0.f};

  for (int k0 = 0; k0 < 256; k0 += 16) {
    __syncthreads();
    for (int i = t; i < 16 * OUT_FEATS; i += 256)
      ldsw[i] = W2[(size_t)(k0 + i / OUT_FEATS) * OUT_FEATS + (i % OUT_FEATS)];
    __syncthreads();

#pragma unroll
    for (int kk = 0; kk < 16; kk += 4) {
      float4 hv[4];
#pragma unroll
      for (int i = 0; i < 4; ++i)
        hv[i] = *(const float4*)&ldsh[(r0 + i) * 256 + k0 + kk];  // broadcast
      float w0 = ldsw[(kk + 0) * OUT_FEATS + cs];
      float w1 = ldsw[(kk + 1) * OUT_FEATS + cs];
      float w2 = ldsw[(kk + 2) * OUT_FEATS + cs];
      float w3 = ldsw[(kk + 3) * OUT_FEATS + cs];
#pragma unroll
      for (int i = 0; i < 4; ++i)
        acc[i] += hv[i].x * w0 + hv[i].y * w1 + hv[i].z * w2 + hv[i].w * w3;
    }
  }

  float alv = (c < OUT_FEATS) ? al2[c] : 0.f;
  float arv = (c < OUT_FEATS) ? ar2[c] : 0.f;
#pragma unroll
  for (int i = 0; i < 4; ++i) {
    int row = n0 + r0 + i;
    if (c < OUT_FEATS) feat2[(size_t)row * OUT_FEATS + c] = acc[i];
    float el = acc[i] * alv;
    float er = acc[i] * arv;
#pragma unroll
    for (int s = 32; s > 0; s >>= 1) {
      el += __shfl_down(el, s, 64);
      er += __shfl_down(er, s, 64);
    }
    if (lane == 0) {
      el2[row] = el;
      er2[row] = er;
    }
  }
}

// ---------------- Layer 2 edge exp-scores (CSR-ordered, node-parallel) ----------------
// Wave w of each block handles node n = blockIdx*4 + w.
__global__ __launch_bounds__(256) void escore2_kernel(
    const int* __restrict__ src_csr, const int* __restrict__ offsets,
    const float* __restrict__ el2, const float* __restrict__ er2,
    float* __restrict__ escore2_csr) {
  int n = blockIdx.x * 4 + (threadIdx.x >> 6);
  if (n >= N_NODES) return;
  int lane = threadIdx.x & 63;
  int off = offsets[n];
  int deg = offsets[n + 1] - off;
  float ern = er2[n];
  for (int j = lane; j < deg; j += 64) {
    int p = off + j;
    escore2_csr[p] = lrelu_exp(el2[src_csr[p]] + ern);
  }
}

// ---------------- Layer 2 aggregate + log_softmax ----------------
__global__ __launch_bounds__(256) void agg2_kernel(
    const int* __restrict__ src_csr, const int* __restrict__ offsets,
    const float* __restrict__ feat2, const float* __restrict__ escore2_csr,
    float* __restrict__ out) {
  __shared__ float ldsacc[4][48];
  __shared__ float ldssum[4];
  int n = blockIdx.x;
  int w = threadIdx.x >> 6;
  int lane = threadIdx.x & 63;
  int off = offsets[n];
  int deg = offsets[n + 1] - off;

  float acc = 0.f;
  float esum = 0.f;
  for (int j = w; j < deg; j += 4) {
    int p = off + j;
    int sn = src_csr[p];         // broadcast
    float a = escore2_csr[p];    // broadcast
    float f = (lane < OUT_FEATS) ? feat2[(size_t)sn * OUT_FEATS + lane] : 0.f;
    acc += a * f;
    esum += a;
  }
  if (lane < OUT_FEATS) ldsacc[w][lane] = acc;
  if (lane == 0) ldssum[w] = esum;
  __syncthreads();

  if (threadIdx.x < 64) {
    int t = threadIdx.x;
    float denom = ldssum[0] + ldssum[1] + ldssum[2] + ldssum[3];
    float inv = 1.f / fmaxf(denom, 1e-9f);
    float logits = 0.f;
    if (t < OUT_FEATS)
      logits = (ldsacc[0][t] + ldsacc[1][t] + ldsacc[2][t] + ldsacc[3][t]) * inv;
    float v = (t < OUT_FEATS) ? logits : -INFINITY;
    float mx = wave_reduce_max(v);
    float ex = (t < OUT_FEATS) ? expf(logits - mx) : 0.f;
    float s = wave_reduce_sum(ex);
    if (t < OUT_FEATS) out[n * OUT_FEATS + t] = logits - mx - logf(s);
  }
}

extern "C" void kernel_launch(void* const* d_in, const int* in_sizes, int n_in,
                              void* d_out, int out_size, void* d_ws, size_t ws_size,
                              hipStream_t stream) {
  const float* features = (const float*)d_in[0];
  const int* src = (const int*)d_in[1];
  const int* dst = (const int*)d_in[2];
  const float* W1 = (const float*)d_in[3];
  const float* al1 = (const float*)d_in[4];
  const float* ar1 = (const float*)d_in[5];
  const float* W2 = (const float*)d_in[6];
  const float* al2 = (const float*)d_in[7];
  const float* ar2 = (const float*)d_in[8];
  float* out = (float*)d_out;

  char* ws = (char*)d_ws;
  size_t o = 0;
  auto alloc = [&](size_t bytes) {
    void* p = ws + o;
    o = (o + bytes + 255) & ~(size_t)255;
    return p;
  };
  unsigned short* feat1h = (unsigned short*)alloc((size_t)N_NODES * 256 * 2);
  float* h2 = (float*)alloc((size_t)N_NODES * 256 * 4);
  float* el1 = (float*)alloc((size_t)N_NODES * 4 * 4);
  float* er1 = (float*)alloc((size_t)N_NODES * 4 * 4);
  float* feat2 = (float*)alloc((size_t)N_NODES * OUT_FEATS * 4);
  float* el2v = (float*)alloc((size_t)N_NODES * 4);
  float* er2v = (float*)alloc((size_t)N_NODES * 4);
  float* escore1_csr = (float*)alloc((size_t)N_EDGES * 4 * 4);
  float* escore2_csr = (float*)alloc((size_t)N_EDGES * 4);
  int* deg = (int*)alloc((size_t)N_NODES * 4);
  int* cursor = (int*)alloc((size_t)N_NODES * 4);
  int* offsets = (int*)alloc((size_t)(N_NODES + 1) * 4);
  int* src_csr = (int*)alloc((size_t)N_EDGES * 4);

  hipMemsetAsync(deg, 0, (size_t)N_NODES * 4, stream);

  count_deg_kernel<<<(N_EDGES + 255) / 256, 256, 0, stream>>>(dst, deg);
  scan_offsets_kernel<<<1, 256, 0, stream>>>(deg, offsets, cursor);
  gemm1_kernel<<<N_NODES / 16, 256, 0, stream>>>(features, W1, al1, ar1, feat1h, el1, er1);
  fill_escore1_kernel<<<(N_EDGES + 255) / 256, 256, 0, stream>>>(src, dst, cursor, src_csr,
                                                                 el1, er1, escore1_csr);
  agg1_kernel<<<N_NODES, 256, 0, stream>>>(src_csr, offsets, feat1h, escore1_csr, h2);
  gemm2_kernel<<<(N_NODES + 15) / 16, 256, 0, stream>>>(h2, W2, al2, ar2, feat2, el2v, er2v);
  escore2_kernel<<<(N_NODES + 3) / 4, 256, 0, stream>>>(src_csr, offsets, el2v, er2v,
                                                        escore2_csr);
  agg2_kernel<<<N_NODES, 256, 0, stream>>>(src_csr, offsets, feat2, escore2_csr, out);
}

// Round 6
// 248.273 us; speedup vs baseline: 1.1726x; 1.1186x over previous
//
#include <hip/hip_runtime.h>
#include <math.h>

#define N_NODES 10000
#define N_EDGES 320000
#define IN_FEATS 256
#define N_HEADS 4
#define N_UNITS 64
#define OUT_FEATS 47
#define NEG_SLOPE 0.2f

typedef __attribute__((ext_vector_type(8))) short bf16x8;
typedef __attribute__((ext_vector_type(4))) float f32x4;

__device__ __forceinline__ float wave_reduce_sum(float v) {
#pragma unroll
  for (int s = 32; s > 0; s >>= 1) v += __shfl_down(v, s, 64);
  return __shfl(v, 0, 64);
}
__device__ __forceinline__ float wave_reduce_max(float v) {
#pragma unroll
  for (int s = 32; s > 0; s >>= 1) v = fmaxf(v, __shfl_down(v, s, 64));
  return __shfl(v, 0, 64);
}

__device__ __forceinline__ float lrelu_exp(float s) {
  s = (s > 0.f) ? s : NEG_SLOPE * s;
  return expf(s);
}

// fp32 -> bf16 round-to-nearest-even
__device__ __forceinline__ unsigned f2bf(float f) {
  unsigned u = __float_as_uint(f);
  return (u + 0x7FFFu + ((u >> 16) & 1u)) >> 16;
}

// ---------------- CSR build ----------------
__global__ void count_deg_kernel(const int* __restrict__ dst, int* __restrict__ deg) {
  int e = blockIdx.x * blockDim.x + threadIdx.x;
  if (e < N_EDGES) atomicAdd(&deg[dst[e]], 1);
}

__global__ void scan_offsets_kernel(const int* __restrict__ deg, int* __restrict__ offsets,
                                    int* __restrict__ cursor) {
  __shared__ int partial[256];
  int t = threadIdx.x;
  const int chunk = (N_NODES + 255) / 256;  // 40
  int start = t * chunk;
  int end = min(start + chunk, N_NODES);
  int sum = 0;
  for (int i = start; i < end; ++i) sum += deg[i];
  partial[t] = sum;
  __syncthreads();
  for (int s = 1; s < 256; s <<= 1) {
    int v = (t >= s) ? partial[t - s] : 0;
    __syncthreads();
    partial[t] += v;
    __syncthreads();
  }
  int base = (t == 0) ? 0 : partial[t - 1];
  for (int i = start; i < end; ++i) {
    offsets[i] = base;
    cursor[i] = base;
    base += deg[i];
  }
  if (t == 0) offsets[N_NODES] = partial[255];
}

// CSR fill + layer-1 edge exp-scores, CSR-ordered.
__global__ void fill_escore1_kernel(const int* __restrict__ src, const int* __restrict__ dst,
                                    int* __restrict__ cursor, int* __restrict__ src_csr,
                                    const float* __restrict__ el1, const float* __restrict__ er1,
                                    float* __restrict__ escore1_csr) {
  int e = blockIdx.x * blockDim.x + threadIdx.x;
  if (e >= N_EDGES) return;
  int d = dst[e];
  int sn = src[e];
  int p = atomicAdd(&cursor[d], 1);
  src_csr[p] = sn;
  float4 el = ((const float4*)el1)[sn];
  float4 er = ((const float4*)er1)[d];
  float4 sc;
  sc.x = lrelu_exp(el.x + er.x);
  sc.y = lrelu_exp(el.y + er.y);
  sc.z = lrelu_exp(el.z + er.z);
  sc.w = lrelu_exp(el.w + er.w);
  ((float4*)escore1_csr)[p] = sc;
}

// ---------------- W1 -> bf16, MFMA B-fragment-linear order ----------------
// flat index o = ((ntg*8 + ks)*64 + lane)*8 + j  maps to
// W1[ks*32 + (lane>>4)*8 + j][ntg*16 + (lane&15)]
__global__ __launch_bounds__(256) void prep_w1_kernel(const float* __restrict__ W1,
                                                      unsigned short* __restrict__ W1f) {
  int o = blockIdx.x * 256 + threadIdx.x;  // 0..65535
  int j = o & 7;
  int lane = (o >> 3) & 63;
  int r = o >> 9;
  int ks = r & 7;
  int ntg = r >> 3;
  int k = ks * 32 + (lane >> 4) * 8 + j;
  int n = ntg * 16 + (lane & 15);
  W1f[o] = (unsigned short)f2bf(W1[k * 256 + n]);
}

// ---------------- Layer 1 GEMM (MFMA bf16): feat1h = features @ W1, fused el1/er1 ----
// 32 rows/block, 4 waves; wave w -> cols [w*64, w*64+64) = 2 m-tiles x 4 n-tiles
// of 16x16, K accumulated by 8 slices of 32 with double-buffered B staging.
__global__ __launch_bounds__(256) void gemm1_kernel(
    const float* __restrict__ features, const unsigned short* __restrict__ W1f,
    const float* __restrict__ al1, const float* __restrict__ ar1,
    unsigned short* __restrict__ feat1h, float* __restrict__ el1, float* __restrict__ er1) {
  __shared__ __align__(16) char smem[49152];
  unsigned short* ldsA = (unsigned short*)smem;                      // 16 KB
  unsigned short* ldsBbuf[2] = {(unsigned short*)(smem + 16384),
                                (unsigned short*)(smem + 32768)};    // 2 x 16 KB
  float* ldsC = (float*)(smem + 16384);                              // 32 KB (reuse B)

  int t = threadIdx.x;
  int n0 = blockIdx.x * 32;
  int lane = t & 63;
  int w = t >> 6;
  int quad = lane >> 4;

  // stage A: 32 rows x 256 k, fp32 -> bf16, XOR-swizzled 16B blocks (bank spread)
  const float4* feat4 = (const float4*)features;
#pragma unroll
  for (int i = 0; i < 8; ++i) {
    int idx = i * 256 + t;
    int m = idx >> 6;
    int kb4 = idx & 63;  // float4 index within row
    float4 f = make_float4(0.f, 0.f, 0.f, 0.f);
    if (n0 + m < N_NODES) f = feat4[(size_t)(n0 + m) * 64 + kb4];
    unsigned u0 = f2bf(f.x) | (f2bf(f.y) << 16);
    unsigned u1 = f2bf(f.z) | (f2bf(f.w) << 16);
    int kb = kb4 >> 1;  // 8-elem block index 0..31
    int di = m * 256 + ((kb ^ (m & 7)) << 3) + ((kb4 & 1) << 2);
    *(uint2*)&ldsA[di] = make_uint2(u0, u1);
  }

  const uint4* W1f4 = (const uint4*)W1f;
  uint4 pb[4];
#pragma unroll
  for (int it = 0; it < 4; ++it) {
    int ci = it * 256 + t;
    pb[it] = W1f4[((ci >> 6) * 8 + 0) * 64 + (ci & 63)];
  }
#pragma unroll
  for (int it = 0; it < 4; ++it) ((uint4*)ldsBbuf[0])[it * 256 + t] = pb[it];
  __syncthreads();

  f32x4 acc[2][4];
#pragma unroll
  for (int mt = 0; mt < 2; ++mt)
#pragma unroll
    for (int nt = 0; nt < 4; ++nt) acc[mt][nt] = 0.f;

  for (int ks = 0; ks < 8; ++ks) {
    if (ks < 7) {
#pragma unroll
      for (int it = 0; it < 4; ++it) {
        int ci = it * 256 + t;
        pb[it] = W1f4[((ci >> 6) * 8 + ks + 1) * 64 + (ci & 63)];
      }
    }
    unsigned short* B = ldsBbuf[ks & 1];
    bf16x8 af[2];
#pragma unroll
    for (int mt = 0; mt < 2; ++mt) {
      int m = mt * 16 + (lane & 15);
      int kb = ks * 4 + quad;
      af[mt] = *(const bf16x8*)&ldsA[m * 256 + ((kb ^ (m & 7)) << 3)];
    }
#pragma unroll
    for (int nt = 0; nt < 4; ++nt) {
      bf16x8 bf = *(const bf16x8*)&B[((w * 4 + nt) * 64 + lane) * 8];
#pragma unroll
      for (int mt = 0; mt < 2; ++mt)
        acc[mt][nt] = __builtin_amdgcn_mfma_f32_16x16x32_bf16(af[mt], bf, acc[mt][nt], 0, 0, 0);
    }
    if (ks < 7) {
      unsigned short* Bn = ldsBbuf[(ks + 1) & 1];
#pragma unroll
      for (int it = 0; it < 4; ++it) ((uint4*)Bn)[it * 256 + t] = pb[it];
    }
    __syncthreads();
  }

  // C tiles -> LDS (f32): row = quad*4+reg, col = lane&15 within each 16x16 tile
#pragma unroll
  for (int mt = 0; mt < 2; ++mt)
#pragma unroll
    for (int nt = 0; nt < 4; ++nt)
#pragma unroll
      for (int r = 0; r < 4; ++r)
        ldsC[(mt * 16 + quad * 4 + r) * 256 + w * 64 + nt * 16 + (lane & 15)] = acc[mt][nt][r];
  __syncthreads();

  // coalesced readout: thread t -> rows w*8..w*8+7, cols lane*4..lane*4+3
  int c = lane * 4;
  int r0 = w * 8;
  float4 alv = ((const float4*)al1)[lane];
  float4 arv = ((const float4*)ar1)[lane];
#pragma unroll
  for (int i = 0; i < 8; ++i) {
    int rl = r0 + i;
    int row = n0 + rl;
    float4 a = *(const float4*)&ldsC[rl * 256 + c];
    bool valid = row < N_NODES;
    if (valid) {
      unsigned p0 = f2bf(a.x) | (f2bf(a.y) << 16);
      unsigned p1 = f2bf(a.z) | (f2bf(a.w) << 16);
      *(uint2*)&feat1h[(size_t)row * 256 + c] = make_uint2(p0, p1);
    }
    float el = a.x * alv.x + a.y * alv.y + a.z * alv.z + a.w * alv.w;
    float er = a.x * arv.x + a.y * arv.y + a.z * arv.z + a.w * arv.w;
#pragma unroll
    for (int s = 8; s > 0; s >>= 1) {
      el += __shfl_down(el, s, 16);
      er += __shfl_down(er, s, 16);
    }
    if ((lane & 15) == 0 && valid) {
      el1[row * 4 + (lane >> 4)] = el;
      er1[row * 4 + (lane >> 4)] = er;
    }
  }
}

// ---------------- Layer 1 aggregate: bf16 gather + precomputed escores ----------------
__global__ __launch_bounds__(256) void agg1_kernel(
    const int* __restrict__ src_csr, const int* __restrict__ offsets,
    const unsigned short* __restrict__ feat1h, const float* __restrict__ escore1_csr,
    float* __restrict__ h2) {
  __shared__ float ldsacc[4][256];
  __shared__ float ldssum[4][4];
  int n = blockIdx.x;
  int w = threadIdx.x >> 6;
  int lane = threadIdx.x & 63;
  int off = offsets[n];
  int deg = offsets[n + 1] - off;
  int hsel = lane >> 4;

  float4 acc = {0.f, 0.f, 0.f, 0.f};
  float4 esum = {0.f, 0.f, 0.f, 0.f};

  for (int j = w; j < deg; j += 4) {
    int sn = src_csr[off + j];                          // wave-uniform broadcast
    float4 a4 = ((const float4*)escore1_csr)[off + j];  // wave-uniform broadcast
    uint2 u = *(const uint2*)&feat1h[(size_t)sn * 256 + lane * 4];  // 512B coalesced
    float f0 = __uint_as_float(u.x << 16);
    float f1 = __uint_as_float(u.x & 0xFFFF0000u);
    float f2 = __uint_as_float(u.y << 16);
    float f3 = __uint_as_float(u.y & 0xFFFF0000u);
    float aw = (hsel == 0) ? a4.x : (hsel == 1) ? a4.y : (hsel == 2) ? a4.z : a4.w;
    acc.x += aw * f0;
    acc.y += aw * f1;
    acc.z += aw * f2;
    acc.w += aw * f3;
    esum.x += a4.x;
    esum.y += a4.y;
    esum.z += a4.z;
    esum.w += a4.w;
  }
  *(float4*)&ldsacc[w][lane * 4] = acc;
  if (lane == 0) *(float4*)&ldssum[w][0] = esum;
  __syncthreads();

  int t = threadIdx.x;
  float tot = ldsacc[0][t] + ldsacc[1][t] + ldsacc[2][t] + ldsacc[3][t];
  int h = t >> 6;
  float denom = ldssum[0][h] + ldssum[1][h] + ldssum[2][h] + ldssum[3][h];
  float val = tot / fmaxf(denom, 1e-9f);
  h2[(size_t)n * 256 + t] = (val > 0.f) ? val : expm1f(val);
}

// ---------------- Layer 2 GEMM: feat2 = h2 @ W2 (16 nodes/block), fused el2/er2 -------
__global__ __launch_bounds__(256) void gemm2_kernel(
    const float* __restrict__ h2, const float* __restrict__ W2,
    const float* __restrict__ al2, const float* __restrict__ ar2,
    float* __restrict__ feat2, float* __restrict__ el2, float* __restrict__ er2) {
  __shared__ float ldsh[16 * 256];
  __shared__ float ldsw[16 * OUT_FEATS];
  int t = threadIdx.x;
  int n0 = blockIdx.x * 16;
  int lane = t & 63;
  int r0 = (t >> 6) * 4;
  int c = lane;
  int cs = (c < OUT_FEATS) ? c : (OUT_FEATS - 1);

  const float4* srch4 = (const float4*)(h2 + (size_t)n0 * 256);
  float4* h4 = (float4*)ldsh;
#pragma unroll
  for (int i = 0; i < 4; ++i) h4[t + i * 256] = srch4[t + i * 256];

  float acc[4] = {0.f, 0.f, 0.f, 0.f};

  for (int k0 = 0; k0 < 256; k0 += 16) {
    __syncthreads();
    for (int i = t; i < 16 * OUT_FEATS; i += 256)
      ldsw[i] = W2[(size_t)(k0 + i / OUT_FEATS) * OUT_FEATS + (i % OUT_FEATS)];
    __syncthreads();

#pragma unroll
    for (int kk = 0; kk < 16; kk += 4) {
      float4 hv[4];
#pragma unroll
      for (int i = 0; i < 4; ++i)
        hv[i] = *(const float4*)&ldsh[(r0 + i) * 256 + k0 + kk];  // broadcast
      float w0 = ldsw[(kk + 0) * OUT_FEATS + cs];
      float w1 = ldsw[(kk + 1) * OUT_FEATS + cs];
      float w2 = ldsw[(kk + 2) * OUT_FEATS + cs];
      float w3 = ldsw[(kk + 3) * OUT_FEATS + cs];
#pragma unroll
      for (int i = 0; i < 4; ++i)
        acc[i] += hv[i].x * w0 + hv[i].y * w1 + hv[i].z * w2 + hv[i].w * w3;
    }
  }

  float alv = (c < OUT_FEATS) ? al2[c] : 0.f;
  float arv = (c < OUT_FEATS) ? ar2[c] : 0.f;
#pragma unroll
  for (int i = 0; i < 4; ++i) {
    int row = n0 + r0 + i;
    if (c < OUT_FEATS) feat2[(size_t)row * OUT_FEATS + c] = acc[i];
    float el = acc[i] * alv;
    float er = acc[i] * arv;
#pragma unroll
    for (int s = 32; s > 0; s >>= 1) {
      el += __shfl_down(el, s, 64);
      er += __shfl_down(er, s, 64);
    }
    if (lane == 0) {
      el2[row] = el;
      er2[row] = er;
    }
  }
}

// ---------------- Layer 2 edge exp-scores (CSR-ordered, node-parallel) ----------------
__global__ __launch_bounds__(256) void escore2_kernel(
    const int* __restrict__ src_csr, const int* __restrict__ offsets,
    const float* __restrict__ el2, const float* __restrict__ er2,
    float* __restrict__ escore2_csr) {
  int n = blockIdx.x * 4 + (threadIdx.x >> 6);
  if (n >= N_NODES) return;
  int lane = threadIdx.x & 63;
  int off = offsets[n];
  int deg = offsets[n + 1] - off;
  float ern = er2[n];
  for (int j = lane; j < deg; j += 64) {
    int p = off + j;
    escore2_csr[p] = lrelu_exp(el2[src_csr[p]] + ern);
  }
}

// ---------------- Layer 2 aggregate + log_softmax ----------------
__global__ __launch_bounds__(256) void agg2_kernel(
    const int* __restrict__ src_csr, const int* __restrict__ offsets,
    const float* __restrict__ feat2, const float* __restrict__ escore2_csr,
    float* __restrict__ out) {
  __shared__ float ldsacc[4][48];
  __shared__ float ldssum[4];
  int n = blockIdx.x;
  int w = threadIdx.x >> 6;
  int lane = threadIdx.x & 63;
  int off = offsets[n];
  int deg = offsets[n + 1] - off;

  float acc = 0.f;
  float esum = 0.f;
  for (int j = w; j < deg; j += 4) {
    int p = off + j;
    int sn = src_csr[p];
    float a = escore2_csr[p];
    float f = (lane < OUT_FEATS) ? feat2[(size_t)sn * OUT_FEATS + lane] : 0.f;
    acc += a * f;
    esum += a;
  }
  if (lane < OUT_FEATS) ldsacc[w][lane] = acc;
  if (lane == 0) ldssum[w] = esum;
  __syncthreads();

  if (threadIdx.x < 64) {
    int t = threadIdx.x;
    float denom = ldssum[0] + ldssum[1] + ldssum[2] + ldssum[3];
    float inv = 1.f / fmaxf(denom, 1e-9f);
    float logits = 0.f;
    if (t < OUT_FEATS)
      logits = (ldsacc[0][t] + ldsacc[1][t] + ldsacc[2][t] + ldsacc[3][t]) * inv;
    float v = (t < OUT_FEATS) ? logits : -INFINITY;
    float mx = wave_reduce_max(v);
    float ex = (t < OUT_FEATS) ? expf(logits - mx) : 0.f;
    float s = wave_reduce_sum(ex);
    if (t < OUT_FEATS) out[n * OUT_FEATS + t] = logits - mx - logf(s);
  }
}

extern "C" void kernel_launch(void* const* d_in, const int* in_sizes, int n_in,
                              void* d_out, int out_size, void* d_ws, size_t ws_size,
                              hipStream_t stream) {
  const float* features = (const float*)d_in[0];
  const int* src = (const int*)d_in[1];
  const int* dst = (const int*)d_in[2];
  const float* W1 = (const float*)d_in[3];
  const float* al1 = (const float*)d_in[4];
  const float* ar1 = (const float*)d_in[5];
  const float* W2 = (const float*)d_in[6];
  const float* al2 = (const float*)d_in[7];
  const float* ar2 = (const float*)d_in[8];
  float* out = (float*)d_out;

  char* ws = (char*)d_ws;
  size_t o = 0;
  auto alloc = [&](size_t bytes) {
    void* p = ws + o;
    o = (o + bytes + 255) & ~(size_t)255;
    return p;
  };
  unsigned short* feat1h = (unsigned short*)alloc((size_t)N_NODES * 256 * 2);
  float* h2 = (float*)alloc((size_t)N_NODES * 256 * 4);
  float* el1 = (float*)alloc((size_t)N_NODES * 4 * 4);
  float* er1 = (float*)alloc((size_t)N_NODES * 4 * 4);
  float* feat2 = (float*)alloc((size_t)N_NODES * OUT_FEATS * 4);
  float* el2v = (float*)alloc((size_t)N_NODES * 4);
  float* er2v = (float*)alloc((size_t)N_NODES * 4);
  float* escore1_csr = (float*)alloc((size_t)N_EDGES * 4 * 4);
  float* escore2_csr = (float*)alloc((size_t)N_EDGES * 4);
  unsigned short* W1f = (unsigned short*)alloc((size_t)256 * 256 * 2);
  int* deg = (int*)alloc((size_t)N_NODES * 4);
  int* cursor = (int*)alloc((size_t)N_NODES * 4);
  int* offsets = (int*)alloc((size_t)(N_NODES + 1) * 4);
  int* src_csr = (int*)alloc((size_t)N_EDGES * 4);

  hipMemsetAsync(deg, 0, (size_t)N_NODES * 4, stream);

  count_deg_kernel<<<(N_EDGES + 255) / 256, 256, 0, stream>>>(dst, deg);
  prep_w1_kernel<<<256, 256, 0, stream>>>(W1, W1f);
  scan_offsets_kernel<<<1, 256, 0, stream>>>(deg, offsets, cursor);
  gemm1_kernel<<<(N_NODES + 31) / 32, 256, 0, stream>>>(features, W1f, al1, ar1, feat1h, el1,
                                                        er1);
  fill_escore1_kernel<<<(N_EDGES + 255) / 256, 256, 0, stream>>>(src, dst, cursor, src_csr,
                                                                 el1, er1, escore1_csr);
  agg1_kernel<<<N_NODES, 256, 0, stream>>>(src_csr, offsets, feat1h, escore1_csr, h2);
  gemm2_kernel<<<(N_NODES + 15) / 16, 256, 0, stream>>>(h2, W2, al2, ar2, feat2, el2v, er2v);
  escore2_kernel<<<(N_NODES + 3) / 4, 256, 0, stream>>>(src_csr, offsets, el2v, er2v,
                                                        escore2_csr);
  agg2_kernel<<<N_NODES, 256, 0, stream>>>(src_csr, offsets, feat2, escore2_csr, out);
}

// Round 8
// 230.187 us; speedup vs baseline: 1.2647x; 1.0786x over previous
//
#include <hip/hip_runtime.h>
#include <math.h>

#define N_NODES 10000
#define N_EDGES 320000
#define IN_FEATS 256
#define N_HEADS 4
#define N_UNITS 64
#define OUT_FEATS 47
#define NEG_SLOPE 0.2f

typedef __attribute__((ext_vector_type(8))) short bf16x8;
typedef __attribute__((ext_vector_type(4))) float f32x4;

__device__ __forceinline__ float wave_reduce_sum(float v) {
#pragma unroll
  for (int s = 32; s > 0; s >>= 1) v += __shfl_down(v, s, 64);
  return __shfl(v, 0, 64);
}
__device__ __forceinline__ float wave_reduce_max(float v) {
#pragma unroll
  for (int s = 32; s > 0; s >>= 1) v = fmaxf(v, __shfl_down(v, s, 64));
  return __shfl(v, 0, 64);
}

__device__ __forceinline__ float lrelu_exp(float s) {
  s = (s > 0.f) ? s : NEG_SLOPE * s;
  return expf(s);
}

// fp32 -> bf16 round-to-nearest-even
__device__ __forceinline__ unsigned f2bf(float f) {
  unsigned u = __float_as_uint(f);
  return (u + 0x7FFFu + ((u >> 16) & 1u)) >> 16;
}

// ---------------- fused prep: deg count + W1/W2 bf16 fragment packing ----------------
// blocks [0,1250): count_deg; [1250,1506): W1 pack; [1506,1554): W2 pack.
// Fragment-linear order for mfma_f32_16x16x32_bf16 B-operand:
//   flat o = ((ntile*8 + ks)*64 + lane)*8 + j  <-  W[k=ks*32+(lane>>4)*8+j][n=ntile*16+(lane&15)]
__global__ __launch_bounds__(256) void prep_kernel(
    const int* __restrict__ dst, int* __restrict__ deg,
    const float* __restrict__ W1, unsigned short* __restrict__ W1f,
    const float* __restrict__ W2, unsigned short* __restrict__ W2f) {
  int b = blockIdx.x;
  int t = threadIdx.x;
  if (b < 1250) {
    int e = b * 256 + t;
    if (e < N_EDGES) atomicAdd(&deg[dst[e]], 1);
  } else if (b < 1250 + 256) {
    int o = (b - 1250) * 256 + t;  // 0..65535
    int j = o & 7;
    int lane = (o >> 3) & 63;
    int r = o >> 9;
    int ks = r & 7;
    int ntg = r >> 3;
    int k = ks * 32 + (lane >> 4) * 8 + j;
    int n = ntg * 16 + (lane & 15);
    W1f[o] = (unsigned short)f2bf(W1[k * 256 + n]);
  } else {
    int o = (b - 1506) * 256 + t;  // 0..12287
    int j = o & 7;
    int lane = (o >> 3) & 63;
    int r = o >> 9;  // 0..23
    int ks = r & 7;
    int ntg = r >> 3;  // 0..2
    int k = ks * 32 + (lane >> 4) * 8 + j;
    int n = ntg * 16 + (lane & 15);
    W2f[o] = (n < OUT_FEATS) ? (unsigned short)f2bf(W2[k * OUT_FEATS + n]) : 0;
  }
}

__global__ void scan_offsets_kernel(const int* __restrict__ deg, int* __restrict__ offsets,
                                    int* __restrict__ cursor) {
  __shared__ int partial[256];
  int t = threadIdx.x;
  const int chunk = (N_NODES + 255) / 256;  // 40
  int start = t * chunk;
  int end = min(start + chunk, N_NODES);
  int sum = 0;
  for (int i = start; i < end; ++i) sum += deg[i];
  partial[t] = sum;
  __syncthreads();
  for (int s = 1; s < 256; s <<= 1) {
    int v = (t >= s) ? partial[t - s] : 0;
    __syncthreads();
    partial[t] += v;
    __syncthreads();
  }
  int base = (t == 0) ? 0 : partial[t - 1];
  for (int i = start; i < end; ++i) {
    offsets[i] = base;
    cursor[i] = base;
    base += deg[i];
  }
  if (t == 0) offsets[N_NODES] = partial[255];
}

// CSR fill + layer-1 edge exp-scores, CSR-ordered.
__global__ void fill_escore1_kernel(const int* __restrict__ src, const int* __restrict__ dst,
                                    int* __restrict__ cursor, int* __restrict__ src_csr,
                                    const float* __restrict__ el1, const float* __restrict__ er1,
                                    float* __restrict__ escore1_csr) {
  int e = blockIdx.x * blockDim.x + threadIdx.x;
  if (e >= N_EDGES) return;
  int d = dst[e];
  int sn = src[e];
  int p = atomicAdd(&cursor[d], 1);
  src_csr[p] = sn;
  float4 el = ((const float4*)el1)[sn];
  float4 er = ((const float4*)er1)[d];
  float4 sc;
  sc.x = lrelu_exp(el.x + er.x);
  sc.y = lrelu_exp(el.y + er.y);
  sc.z = lrelu_exp(el.z + er.z);
  sc.w = lrelu_exp(el.w + er.w);
  ((float4*)escore1_csr)[p] = sc;
}

// ---------------- Layer 1 GEMM (MFMA bf16): feat1h = features @ W1, fused el1/er1 ----
__global__ __launch_bounds__(256) void gemm1_kernel(
    const float* __restrict__ features, const unsigned short* __restrict__ W1f,
    const float* __restrict__ al1, const float* __restrict__ ar1,
    unsigned short* __restrict__ feat1h, float* __restrict__ el1, float* __restrict__ er1) {
  __shared__ __align__(16) char smem[49152];
  unsigned short* ldsA = (unsigned short*)smem;                    // 16 KB
  unsigned short* ldsBbuf[2] = {(unsigned short*)(smem + 16384),
                                (unsigned short*)(smem + 32768)};  // 2 x 16 KB
  float* ldsC = (float*)(smem + 16384);                            // 32 KB (reuse B)

  int t = threadIdx.x;
  int n0 = blockIdx.x * 32;
  int lane = t & 63;
  int w = t >> 6;
  int quad = lane >> 4;

  const float4* feat4 = (const float4*)features;
#pragma unroll
  for (int i = 0; i < 8; ++i) {
    int idx = i * 256 + t;
    int m = idx >> 6;
    int kb4 = idx & 63;
    float4 f = make_float4(0.f, 0.f, 0.f, 0.f);
    if (n0 + m < N_NODES) f = feat4[(size_t)(n0 + m) * 64 + kb4];
    unsigned u0 = f2bf(f.x) | (f2bf(f.y) << 16);
    unsigned u1 = f2bf(f.z) | (f2bf(f.w) << 16);
    int kb = kb4 >> 1;
    int di = m * 256 + ((kb ^ (m & 7)) << 3) + ((kb4 & 1) << 2);
    *(uint2*)&ldsA[di] = make_uint2(u0, u1);
  }

  const uint4* W1f4 = (const uint4*)W1f;
  uint4 pb[4];
#pragma unroll
  for (int it = 0; it < 4; ++it) {
    int ci = it * 256 + t;
    pb[it] = W1f4[((ci >> 6) * 8 + 0) * 64 + (ci & 63)];
  }
#pragma unroll
  for (int it = 0; it < 4; ++it) ((uint4*)ldsBbuf[0])[it * 256 + t] = pb[it];
  __syncthreads();

  f32x4 acc[2][4];
#pragma unroll
  for (int mt = 0; mt < 2; ++mt)
#pragma unroll
    for (int nt = 0; nt < 4; ++nt) acc[mt][nt] = 0.f;

  for (int ks = 0; ks < 8; ++ks) {
    if (ks < 7) {
#pragma unroll
      for (int it = 0; it < 4; ++it) {
        int ci = it * 256 + t;
        pb[it] = W1f4[((ci >> 6) * 8 + ks + 1) * 64 + (ci & 63)];
      }
    }
    unsigned short* B = ldsBbuf[ks & 1];
    bf16x8 af[2];
#pragma unroll
    for (int mt = 0; mt < 2; ++mt) {
      int m = mt * 16 + (lane & 15);
      int kb = ks * 4 + quad;
      af[mt] = *(const bf16x8*)&ldsA[m * 256 + ((kb ^ (m & 7)) << 3)];
    }
#pragma unroll
    for (int nt = 0; nt < 4; ++nt) {
      bf16x8 bf = *(const bf16x8*)&B[((w * 4 + nt) * 64 + lane) * 8];
#pragma unroll
      for (int mt = 0; mt < 2; ++mt)
        acc[mt][nt] = __builtin_amdgcn_mfma_f32_16x16x32_bf16(af[mt], bf, acc[mt][nt], 0, 0, 0);
    }
    if (ks < 7) {
      unsigned short* Bn = ldsBbuf[(ks + 1) & 1];
#pragma unroll
      for (int it = 0; it < 4; ++it) ((uint4*)Bn)[it * 256 + t] = pb[it];
    }
    __syncthreads();
  }

#pragma unroll
  for (int mt = 0; mt < 2; ++mt)
#pragma unroll
    for (int nt = 0; nt < 4; ++nt)
#pragma unroll
      for (int r = 0; r < 4; ++r)
        ldsC[(mt * 16 + quad * 4 + r) * 256 + w * 64 + nt * 16 + (lane & 15)] = acc[mt][nt][r];
  __syncthreads();

  int c = lane * 4;
  int r0 = w * 8;
  float4 alv = ((const float4*)al1)[lane];
  float4 arv = ((const float4*)ar1)[lane];
#pragma unroll
  for (int i = 0; i < 8; ++i) {
    int rl = r0 + i;
    int row = n0 + rl;
    float4 a = *(const float4*)&ldsC[rl * 256 + c];
    bool valid = row < N_NODES;
    if (valid) {
      unsigned p0 = f2bf(a.x) | (f2bf(a.y) << 16);
      unsigned p1 = f2bf(a.z) | (f2bf(a.w) << 16);
      *(uint2*)&feat1h[(size_t)row * 256 + c] = make_uint2(p0, p1);
    }
    float el = a.x * alv.x + a.y * alv.y + a.z * alv.z + a.w * alv.w;
    float er = a.x * arv.x + a.y * arv.y + a.z * arv.z + a.w * arv.w;
#pragma unroll
    for (int s = 8; s > 0; s >>= 1) {
      el += __shfl_down(el, s, 16);
      er += __shfl_down(er, s, 16);
    }
    if ((lane & 15) == 0 && valid) {
      el1[row * 4 + (lane >> 4)] = el;
      er1[row * 4 + (lane >> 4)] = er;
    }
  }
}

// ---------------- Layer 1 aggregate: bf16 gather + precomputed escores ----------------
__global__ __launch_bounds__(256) void agg1_kernel(
    const int* __restrict__ src_csr, const int* __restrict__ offsets,
    const unsigned short* __restrict__ feat1h, const float* __restrict__ escore1_csr,
    float* __restrict__ h2) {
  __shared__ float ldsacc[4][256];
  __shared__ float ldssum[4][4];
  int n = blockIdx.x;
  int w = threadIdx.x >> 6;
  int lane = threadIdx.x & 63;
  int off = offsets[n];
  int deg = offsets[n + 1] - off;
  int hsel = lane >> 4;

  float4 acc = {0.f, 0.f, 0.f, 0.f};
  float4 esum = {0.f, 0.f, 0.f, 0.f};

  for (int j = w; j < deg; j += 4) {
    int sn = src_csr[off + j];
    float4 a4 = ((const float4*)escore1_csr)[off + j];
    uint2 u = *(const uint2*)&feat1h[(size_t)sn * 256 + lane * 4];
    float f0 = __uint_as_float(u.x << 16);
    float f1 = __uint_as_float(u.x & 0xFFFF0000u);
    float f2 = __uint_as_float(u.y << 16);
    float f3 = __uint_as_float(u.y & 0xFFFF0000u);
    float aw = (hsel == 0) ? a4.x : (hsel == 1) ? a4.y : (hsel == 2) ? a4.z : a4.w;
    acc.x += aw * f0;
    acc.y += aw * f1;
    acc.z += aw * f2;
    acc.w += aw * f3;
    esum.x += a4.x;
    esum.y += a4.y;
    esum.z += a4.z;
    esum.w += a4.w;
  }
  *(float4*)&ldsacc[w][lane * 4] = acc;
  if (lane == 0) *(float4*)&ldssum[w][0] = esum;
  __syncthreads();

  int t = threadIdx.x;
  float tot = ldsacc[0][t] + ldsacc[1][t] + ldsacc[2][t] + ldsacc[3][t];
  int h = t >> 6;
  float denom = ldssum[0][h] + ldssum[1][h] + ldssum[2][h] + ldssum[3][h];
  float val = tot / fmaxf(denom, 1e-9f);
  h2[(size_t)n * 256 + t] = (val > 0.f) ? val : expm1f(val);
}

// ---------------- Layer 2 GEMM (MFMA bf16): feat2 = h2 @ W2, fused el2/er2 ----------
// 64 rows/block, wave w = m-tile w; 3 n-tiles (48 cols, col 47 zero-padded);
// whole A (64x256 bf16) + whole B (256x48 bf16) staged once, one barrier.
__global__ __launch_bounds__(256) void gemm2_kernel(
    const float* __restrict__ h2, const unsigned short* __restrict__ W2f,
    const float* __restrict__ al2, const float* __restrict__ ar2,
    float* __restrict__ feat2, float* __restrict__ el2, float* __restrict__ er2) {
  __shared__ __align__(16) char smem[32768 + 24576];
  unsigned short* ldsA = (unsigned short*)smem;            // 32 KB
  unsigned short* ldsB = (unsigned short*)(smem + 32768);  // 24 KB
  float* ldsC = (float*)(smem + 32768);                    // 12 KB (reuse B)

  int t = threadIdx.x;
  int n0 = blockIdx.x * 64;
  int lane = t & 63;
  int w = t >> 6;
  int quad = lane >> 4;

  // stage A: 64 rows x 256, fp32 -> bf16, XOR-swizzled
  const float4* h4 = (const float4*)h2;
#pragma unroll
  for (int i = 0; i < 16; ++i) {
    int idx = i * 256 + t;  // 0..4095
    int m = idx >> 6;
    int kb4 = idx & 63;
    float4 f = make_float4(0.f, 0.f, 0.f, 0.f);
    if (n0 + m < N_NODES) f = h4[(size_t)(n0 + m) * 64 + kb4];
    unsigned u0 = f2bf(f.x) | (f2bf(f.y) << 16);
    unsigned u1 = f2bf(f.z) | (f2bf(f.w) << 16);
    int kb = kb4 >> 1;
    int di = m * 256 + ((kb ^ (m & 7)) << 3) + ((kb4 & 1) << 2);
    *(uint2*)&ldsA[di] = make_uint2(u0, u1);
  }
  // stage B: 1536 uint4
  const uint4* Bg = (const uint4*)W2f;
#pragma unroll
  for (int i = 0; i < 6; ++i) ((uint4*)ldsB)[i * 256 + t] = Bg[i * 256 + t];
  __syncthreads();

  f32x4 acc[3];
#pragma unroll
  for (int nt = 0; nt < 3; ++nt) acc[nt] = 0.f;

#pragma unroll
  for (int ks = 0; ks < 8; ++ks) {
    int m = w * 16 + (lane & 15);
    int kb = ks * 4 + quad;
    bf16x8 af = *(const bf16x8*)&ldsA[m * 256 + ((kb ^ (m & 7)) << 3)];
#pragma unroll
    for (int nt = 0; nt < 3; ++nt) {
      bf16x8 bf = *(const bf16x8*)&ldsB[((nt * 8 + ks) * 64 + lane) * 8];
      acc[nt] = __builtin_amdgcn_mfma_f32_16x16x32_bf16(af, bf, acc[nt], 0, 0, 0);
    }
  }
  __syncthreads();  // all B reads done before C overwrites

#pragma unroll
  for (int nt = 0; nt < 3; ++nt)
#pragma unroll
    for (int r = 0; r < 4; ++r)
      ldsC[(w * 16 + quad * 4 + r) * 48 + nt * 16 + (lane & 15)] = acc[nt][r];
  __syncthreads();

  // feat2 write: 64 rows x 47 cols
#pragma unroll
  for (int i = 0; i < 12; ++i) {
    int idx = i * 256 + t;  // 0..3071
    int row = idx / 48;
    int col = idx - row * 48;
    int grow = n0 + row;
    if (col < OUT_FEATS && grow < N_NODES) feat2[(size_t)grow * OUT_FEATS + col] = ldsC[idx];
  }
  // el2/er2: wave w handles rows w*16..w*16+15
  float al = (lane < OUT_FEATS) ? al2[lane] : 0.f;
  float ar = (lane < OUT_FEATS) ? ar2[lane] : 0.f;
#pragma unroll
  for (int i = 0; i < 16; ++i) {
    int row = w * 16 + i;
    int grow = n0 + row;
    float cv = (lane < OUT_FEATS) ? ldsC[row * 48 + lane] : 0.f;
    float el = cv * al;
    float er = cv * ar;
#pragma unroll
    for (int s = 32; s > 0; s >>= 1) {
      el += __shfl_down(el, s, 64);
      er += __shfl_down(er, s, 64);
    }
    if (lane == 0 && grow < N_NODES) {
      el2[grow] = el;
      er2[grow] = er;
    }
  }
}

// ---------------- Layer 2 aggregate + fused scores + log_softmax ----------------
// Phase A: one lrelu_exp per edge, parallel across 256 threads -> LDS.
// Phase B: 4 waves aggregate reading LDS scores. NOTE: every lane of a wave
// iterates the SAME edges, so lane 0's esum already equals the wave partial —
// do NOT wave-reduce it (round-7 bug: 64x denominator inflation).
__global__ __launch_bounds__(256) void agg2_kernel(
    const int* __restrict__ src_csr, const int* __restrict__ offsets,
    const float* __restrict__ feat2, const float* __restrict__ el2,
    const float* __restrict__ er2, float* __restrict__ out) {
  __shared__ float lds_s[256];
  __shared__ float ldsacc[4][48];
  __shared__ float ldssum[4];
  int n = blockIdx.x;
  int t = threadIdx.x;
  int w = t >> 6;
  int lane = t & 63;
  int off = offsets[n];
  int deg = offsets[n + 1] - off;
  float ern = er2[n];

  float acc = 0.f;
  float esum = 0.f;
  for (int c0 = 0; c0 < deg; c0 += 256) {
    int cnt = min(256, deg - c0);
    if (t < cnt) lds_s[t] = lrelu_exp(el2[src_csr[off + c0 + t]] + ern);
    __syncthreads();
    for (int j = w; j < cnt; j += 4) {
      int sn = src_csr[off + c0 + j];  // broadcast
      float a = lds_s[j];
      float f = (lane < OUT_FEATS) ? feat2[(size_t)sn * OUT_FEATS + lane] : 0.f;
      acc += a * f;
      esum += a;
    }
    __syncthreads();
  }
  if (lane < OUT_FEATS) ldsacc[w][lane] = acc;
  if (lane == 0) ldssum[w] = esum;  // all lanes identical; take lane 0 (no reduce!)
  __syncthreads();

  if (t < 64) {
    float denom = ldssum[0] + ldssum[1] + ldssum[2] + ldssum[3];
    float inv = 1.f / fmaxf(denom, 1e-9f);
    float logits = 0.f;
    if (t < OUT_FEATS)
      logits = (ldsacc[0][t] + ldsacc[1][t] + ldsacc[2][t] + ldsacc[3][t]) * inv;
    float v = (t < OUT_FEATS) ? logits : -INFINITY;
    float mx = wave_reduce_max(v);
    float ex = (t < OUT_FEATS) ? expf(logits - mx) : 0.f;
    float s = wave_reduce_sum(ex);
    if (t < OUT_FEATS) out[n * OUT_FEATS + t] = logits - mx - logf(s);
  }
}

extern "C" void kernel_launch(void* const* d_in, const int* in_sizes, int n_in,
                              void* d_out, int out_size, void* d_ws, size_t ws_size,
                              hipStream_t stream) {
  const float* features = (const float*)d_in[0];
  const int* src = (const int*)d_in[1];
  const int* dst = (const int*)d_in[2];
  const float* W1 = (const float*)d_in[3];
  const float* al1 = (const float*)d_in[4];
  const float* ar1 = (const float*)d_in[5];
  const float* W2 = (const float*)d_in[6];
  const float* al2 = (const float*)d_in[7];
  const float* ar2 = (const float*)d_in[8];
  float* out = (float*)d_out;

  char* ws = (char*)d_ws;
  size_t o = 0;
  auto alloc = [&](size_t bytes) {
    void* p = ws + o;
    o = (o + bytes + 255) & ~(size_t)255;
    return p;
  };
  unsigned short* feat1h = (unsigned short*)alloc((size_t)N_NODES * 256 * 2);
  float* h2 = (float*)alloc((size_t)N_NODES * 256 * 4);
  float* el1 = (float*)alloc((size_t)N_NODES * 4 * 4);
  float* er1 = (float*)alloc((size_t)N_NODES * 4 * 4);
  float* feat2 = (float*)alloc((size_t)N_NODES * OUT_FEATS * 4);
  float* el2v = (float*)alloc((size_t)N_NODES * 4);
  float* er2v = (float*)alloc((size_t)N_NODES * 4);
  float* escore1_csr = (float*)alloc((size_t)N_EDGES * 4 * 4);
  unsigned short* W1f = (unsigned short*)alloc((size_t)256 * 256 * 2);
  unsigned short* W2f = (unsigned short*)alloc((size_t)256 * 48 * 2);
  int* deg = (int*)alloc((size_t)N_NODES * 4);
  int* cursor = (int*)alloc((size_t)N_NODES * 4);
  int* offsets = (int*)alloc((size_t)(N_NODES + 1) * 4);
  int* src_csr = (int*)alloc((size_t)N_EDGES * 4);

  hipMemsetAsync(deg, 0, (size_t)N_NODES * 4, stream);

  prep_kernel<<<1554, 256, 0, stream>>>(dst, deg, W1, W1f, W2, W2f);
  scan_offsets_kernel<<<1, 256, 0, stream>>>(deg, offsets, cursor);
  gemm1_kernel<<<(N_NODES + 31) / 32, 256, 0, stream>>>(features, W1f, al1, ar1, feat1h, el1,
                                                        er1);
  fill_escore1_kernel<<<(N_EDGES + 255) / 256, 256, 0, stream>>>(src, dst, cursor, src_csr,
                                                                 el1, er1, escore1_csr);
  agg1_kernel<<<N_NODES, 256, 0, stream>>>(src_csr, offsets, feat1h, escore1_csr, h2);
  gemm2_kernel<<<(N_NODES + 63) / 64, 256, 0, stream>>>(h2, W2f, al2, ar2, feat2, el2v, er2v);
  agg2_kernel<<<N_NODES, 256, 0, stream>>>(src_csr, offsets, feat2, el2v, er2v, out);
}

// Round 9
// 220.382 us; speedup vs baseline: 1.3210x; 1.0445x over previous
//
#include <hip/hip_runtime.h>
#include <math.h>

#define N_NODES 10000
#define N_EDGES 320000
#define IN_FEATS 256
#define N_HEADS 4
#define N_UNITS 64
#define OUT_FEATS 47
#define NEG_SLOPE 0.2f

typedef __attribute__((ext_vector_type(8))) short bf16x8;
typedef __attribute__((ext_vector_type(4))) float f32x4;

__device__ __forceinline__ float wave_reduce_sum(float v) {
#pragma unroll
  for (int s = 32; s > 0; s >>= 1) v += __shfl_down(v, s, 64);
  return __shfl(v, 0, 64);
}
__device__ __forceinline__ float wave_reduce_max(float v) {
#pragma unroll
  for (int s = 32; s > 0; s >>= 1) v = fmaxf(v, __shfl_down(v, s, 64));
  return __shfl(v, 0, 64);
}

__device__ __forceinline__ float lrelu_exp(float s) {
  s = (s > 0.f) ? s : NEG_SLOPE * s;
  return expf(s);
}

// fp32 -> bf16 round-to-nearest-even
__device__ __forceinline__ unsigned f2bf(float f) {
  unsigned u = __float_as_uint(f);
  return (u + 0x7FFFu + ((u >> 16) & 1u)) >> 16;
}

// ---------------- fused prep: deg count + W1/W2 packing + wa/wb ----------------
// blocks [0,1250): count_deg; [1250,1506): W1 pack; [1506,1554): W2 pack;
// 1554: wa = W2 @ al2, wb = W2 @ ar2 (for agg1's fused el2/er2).
__global__ __launch_bounds__(256) void prep_kernel(
    const int* __restrict__ dst, int* __restrict__ deg,
    const float* __restrict__ W1, unsigned short* __restrict__ W1f,
    const float* __restrict__ W2, unsigned short* __restrict__ W2f,
    const float* __restrict__ al2, const float* __restrict__ ar2,
    float* __restrict__ wa, float* __restrict__ wb) {
  int b = blockIdx.x;
  int t = threadIdx.x;
  if (b < 1250) {
    int e = b * 256 + t;
    if (e < N_EDGES) atomicAdd(&deg[dst[e]], 1);
  } else if (b < 1250 + 256) {
    int o = (b - 1250) * 256 + t;  // 0..65535
    int j = o & 7;
    int lane = (o >> 3) & 63;
    int r = o >> 9;
    int ks = r & 7;
    int ntg = r >> 3;
    int k = ks * 32 + (lane >> 4) * 8 + j;
    int n = ntg * 16 + (lane & 15);
    W1f[o] = (unsigned short)f2bf(W1[k * 256 + n]);
  } else if (b < 1554) {
    int o = (b - 1506) * 256 + t;  // 0..12287
    int j = o & 7;
    int lane = (o >> 3) & 63;
    int r = o >> 9;  // 0..23
    int ks = r & 7;
    int ntg = r >> 3;  // 0..2
    int k = ks * 32 + (lane >> 4) * 8 + j;
    int n = ntg * 16 + (lane & 15);
    W2f[o] = (n < OUT_FEATS) ? (unsigned short)f2bf(W2[k * OUT_FEATS + n]) : 0;
  } else {
    float a = 0.f, r = 0.f;
    for (int c = 0; c < OUT_FEATS; ++c) {
      float w = W2[t * OUT_FEATS + c];
      a += w * al2[c];
      r += w * ar2[c];
    }
    wa[t] = a;
    wb[t] = r;
  }
}

__global__ void scan_offsets_kernel(const int* __restrict__ deg, int* __restrict__ offsets,
                                    int* __restrict__ cursor) {
  __shared__ int partial[256];
  int t = threadIdx.x;
  const int chunk = (N_NODES + 255) / 256;  // 40
  int start = t * chunk;
  int end = min(start + chunk, N_NODES);
  int sum = 0;
  for (int i = start; i < end; ++i) sum += deg[i];
  partial[t] = sum;
  __syncthreads();
  for (int s = 1; s < 256; s <<= 1) {
    int v = (t >= s) ? partial[t - s] : 0;
    __syncthreads();
    partial[t] += v;
    __syncthreads();
  }
  int base = (t == 0) ? 0 : partial[t - 1];
  for (int i = start; i < end; ++i) {
    offsets[i] = base;
    cursor[i] = base;
    base += deg[i];
  }
  if (t == 0) offsets[N_NODES] = partial[255];
}

// CSR fill + layer-1 edge exp-scores, CSR-ordered.
__global__ void fill_escore1_kernel(const int* __restrict__ src, const int* __restrict__ dst,
                                    int* __restrict__ cursor, int* __restrict__ src_csr,
                                    const float* __restrict__ el1, const float* __restrict__ er1,
                                    float* __restrict__ escore1_csr) {
  int e = blockIdx.x * blockDim.x + threadIdx.x;
  if (e >= N_EDGES) return;
  int d = dst[e];
  int sn = src[e];
  int p = atomicAdd(&cursor[d], 1);
  src_csr[p] = sn;
  float4 el = ((const float4*)el1)[sn];
  float4 er = ((const float4*)er1)[d];
  float4 sc;
  sc.x = lrelu_exp(el.x + er.x);
  sc.y = lrelu_exp(el.y + er.y);
  sc.z = lrelu_exp(el.z + er.z);
  sc.w = lrelu_exp(el.w + er.w);
  ((float4*)escore1_csr)[p] = sc;
}

// ---------------- Layer 1 GEMM (MFMA bf16): feat1h = features @ W1, fused el1/er1 ----
__global__ __launch_bounds__(256) void gemm1_kernel(
    const float* __restrict__ features, const unsigned short* __restrict__ W1f,
    const float* __restrict__ al1, const float* __restrict__ ar1,
    unsigned short* __restrict__ feat1h, float* __restrict__ el1, float* __restrict__ er1) {
  __shared__ __align__(16) char smem[49152];
  unsigned short* ldsA = (unsigned short*)smem;                    // 16 KB
  unsigned short* ldsBbuf[2] = {(unsigned short*)(smem + 16384),
                                (unsigned short*)(smem + 32768)};  // 2 x 16 KB
  float* ldsC = (float*)(smem + 16384);                            // 32 KB (reuse B)

  int t = threadIdx.x;
  int n0 = blockIdx.x * 32;
  int lane = t & 63;
  int w = t >> 6;
  int quad = lane >> 4;

  const float4* feat4 = (const float4*)features;
#pragma unroll
  for (int i = 0; i < 8; ++i) {
    int idx = i * 256 + t;
    int m = idx >> 6;
    int kb4 = idx & 63;
    float4 f = make_float4(0.f, 0.f, 0.f, 0.f);
    if (n0 + m < N_NODES) f = feat4[(size_t)(n0 + m) * 64 + kb4];
    unsigned u0 = f2bf(f.x) | (f2bf(f.y) << 16);
    unsigned u1 = f2bf(f.z) | (f2bf(f.w) << 16);
    int kb = kb4 >> 1;
    int di = m * 256 + ((kb ^ (m & 7)) << 3) + ((kb4 & 1) << 2);
    *(uint2*)&ldsA[di] = make_uint2(u0, u1);
  }

  const uint4* W1f4 = (const uint4*)W1f;
  uint4 pb[4];
#pragma unroll
  for (int it = 0; it < 4; ++it) {
    int ci = it * 256 + t;
    pb[it] = W1f4[((ci >> 6) * 8 + 0) * 64 + (ci & 63)];
  }
#pragma unroll
  for (int it = 0; it < 4; ++it) ((uint4*)ldsBbuf[0])[it * 256 + t] = pb[it];
  __syncthreads();

  f32x4 acc[2][4];
#pragma unroll
  for (int mt = 0; mt < 2; ++mt)
#pragma unroll
    for (int nt = 0; nt < 4; ++nt) acc[mt][nt] = 0.f;

  for (int ks = 0; ks < 8; ++ks) {
    if (ks < 7) {
#pragma unroll
      for (int it = 0; it < 4; ++it) {
        int ci = it * 256 + t;
        pb[it] = W1f4[((ci >> 6) * 8 + ks + 1) * 64 + (ci & 63)];
      }
    }
    unsigned short* B = ldsBbuf[ks & 1];
    bf16x8 af[2];
#pragma unroll
    for (int mt = 0; mt < 2; ++mt) {
      int m = mt * 16 + (lane & 15);
      int kb = ks * 4 + quad;
      af[mt] = *(const bf16x8*)&ldsA[m * 256 + ((kb ^ (m & 7)) << 3)];
    }
#pragma unroll
    for (int nt = 0; nt < 4; ++nt) {
      bf16x8 bf = *(const bf16x8*)&B[((w * 4 + nt) * 64 + lane) * 8];
#pragma unroll
      for (int mt = 0; mt < 2; ++mt)
        acc[mt][nt] = __builtin_amdgcn_mfma_f32_16x16x32_bf16(af[mt], bf, acc[mt][nt], 0, 0, 0);
    }
    if (ks < 7) {
      unsigned short* Bn = ldsBbuf[(ks + 1) & 1];
#pragma unroll
      for (int it = 0; it < 4; ++it) ((uint4*)Bn)[it * 256 + t] = pb[it];
    }
    __syncthreads();
  }

#pragma unroll
  for (int mt = 0; mt < 2; ++mt)
#pragma unroll
    for (int nt = 0; nt < 4; ++nt)
#pragma unroll
      for (int r = 0; r < 4; ++r)
        ldsC[(mt * 16 + quad * 4 + r) * 256 + w * 64 + nt * 16 + (lane & 15)] = acc[mt][nt][r];
  __syncthreads();

  int c = lane * 4;
  int r0 = w * 8;
  float4 alv = ((const float4*)al1)[lane];
  float4 arv = ((const float4*)ar1)[lane];
#pragma unroll
  for (int i = 0; i < 8; ++i) {
    int rl = r0 + i;
    int row = n0 + rl;
    float4 a = *(const float4*)&ldsC[rl * 256 + c];
    bool valid = row < N_NODES;
    if (valid) {
      unsigned p0 = f2bf(a.x) | (f2bf(a.y) << 16);
      unsigned p1 = f2bf(a.z) | (f2bf(a.w) << 16);
      *(uint2*)&feat1h[(size_t)row * 256 + c] = make_uint2(p0, p1);
    }
    float el = a.x * alv.x + a.y * alv.y + a.z * alv.z + a.w * alv.w;
    float er = a.x * arv.x + a.y * arv.y + a.z * arv.z + a.w * arv.w;
#pragma unroll
    for (int s = 8; s > 0; s >>= 1) {
      el += __shfl_down(el, s, 16);
      er += __shfl_down(er, s, 16);
    }
    if ((lane & 15) == 0 && valid) {
      el1[row * 4 + (lane >> 4)] = el;
      er1[row * 4 + (lane >> 4)] = er;
    }
  }
}

// ---------------- Layer 1 aggregate: 2 edges/wave-iter, bf16 h2 out, fused el2/er2 ----
// Half-wave (32 lanes) per edge: lane hl=lane&31 covers dims hl*8..hl*8+7 (uint4).
// Wave w, half h process edges p = 2w+h, 2w+h+8, ... ELU + el2/er2 dot in epilogue.
__global__ __launch_bounds__(256) void agg1_kernel(
    const int* __restrict__ src_csr, const int* __restrict__ offsets,
    const unsigned short* __restrict__ feat1h, const float* __restrict__ escore1_csr,
    const float* __restrict__ wa, const float* __restrict__ wb,
    unsigned short* __restrict__ h2h, float* __restrict__ el2, float* __restrict__ er2) {
  __shared__ float ldsacc[4][256];
  __shared__ float ldssum[4][4];
  __shared__ float ldse[4], ldsr[4];
  int n = blockIdx.x;
  int t = threadIdx.x;
  int w = t >> 6;
  int lane = t & 63;
  int half = lane >> 5;
  int hl = lane & 31;
  int off = offsets[n];
  int deg = offsets[n + 1] - off;
  int head = hl >> 3;

  float acc[8];
#pragma unroll
  for (int r = 0; r < 8; ++r) acc[r] = 0.f;
  float4 esum = {0.f, 0.f, 0.f, 0.f};

  for (int p = w * 2 + half; p < deg; p += 8) {
    int sn = src_csr[off + p];                          // half-uniform broadcast
    float4 a4 = ((const float4*)escore1_csr)[off + p];  // half-uniform broadcast
    uint4 u = *(const uint4*)&feat1h[(size_t)sn * 256 + hl * 8];  // 512B/edge coalesced
    float aw = (head == 0) ? a4.x : (head == 1) ? a4.y : (head == 2) ? a4.z : a4.w;
    acc[0] += aw * __uint_as_float(u.x << 16);
    acc[1] += aw * __uint_as_float(u.x & 0xFFFF0000u);
    acc[2] += aw * __uint_as_float(u.y << 16);
    acc[3] += aw * __uint_as_float(u.y & 0xFFFF0000u);
    acc[4] += aw * __uint_as_float(u.z << 16);
    acc[5] += aw * __uint_as_float(u.z & 0xFFFF0000u);
    acc[6] += aw * __uint_as_float(u.w << 16);
    acc[7] += aw * __uint_as_float(u.w & 0xFFFF0000u);
    esum.x += a4.x;
    esum.y += a4.y;
    esum.z += a4.z;
    esum.w += a4.w;
  }
  // combine the two halves (lane l += lane l+32)
#pragma unroll
  for (int r = 0; r < 8; ++r) acc[r] += __shfl_down(acc[r], 32, 64);
  esum.x += __shfl_down(esum.x, 32, 64);
  esum.y += __shfl_down(esum.y, 32, 64);
  esum.z += __shfl_down(esum.z, 32, 64);
  esum.w += __shfl_down(esum.w, 32, 64);
  if (half == 0) {
    *(float4*)&ldsacc[w][hl * 8] = make_float4(acc[0], acc[1], acc[2], acc[3]);
    *(float4*)&ldsacc[w][hl * 8 + 4] = make_float4(acc[4], acc[5], acc[6], acc[7]);
  }
  if (lane == 0) *(float4*)&ldssum[w][0] = esum;
  __syncthreads();

  float tot = ldsacc[0][t] + ldsacc[1][t] + ldsacc[2][t] + ldsacc[3][t];
  int h = t >> 6;
  float denom = ldssum[0][h] + ldssum[1][h] + ldssum[2][h] + ldssum[3][h];
  float val = tot / fmaxf(denom, 1e-9f);
  val = (val > 0.f) ? val : expm1f(val);  // ELU

  // fused el2/er2: dot(h2_row, wa/wb) block-reduce
  float elp = val * wa[t];
  float erp = val * wb[t];
#pragma unroll
  for (int s = 32; s > 0; s >>= 1) {
    elp += __shfl_down(elp, s, 64);
    erp += __shfl_down(erp, s, 64);
  }
  if (lane == 0) {
    ldse[w] = elp;
    ldsr[w] = erp;
  }
  // bf16 pack in pairs (lane even packs [t, t+1])
  float vhi = __shfl_down(val, 1, 64);
  if (!(t & 1)) *(unsigned*)&h2h[(size_t)n * 256 + t] = f2bf(val) | (f2bf(vhi) << 16);
  __syncthreads();
  if (t == 0) {
    el2[n] = ldse[0] + ldse[1] + ldse[2] + ldse[3];
    er2[n] = ldsr[0] + ldsr[1] + ldsr[2] + ldsr[3];
  }
}

// ---------------- Layer 2 GEMM (MFMA bf16): feat2p(48-padded) = h2h @ W2 ----------
__global__ __launch_bounds__(256) void gemm2_kernel(
    const unsigned short* __restrict__ h2h, const unsigned short* __restrict__ W2f,
    float* __restrict__ feat2p) {
  __shared__ __align__(16) char smem[32768 + 24576];
  unsigned short* ldsA = (unsigned short*)smem;            // 32 KB
  unsigned short* ldsB = (unsigned short*)(smem + 32768);  // 24 KB
  float* ldsC = (float*)(smem + 32768);                    // 12 KB (reuse B)

  int t = threadIdx.x;
  int n0 = blockIdx.x * 64;
  int lane = t & 63;
  int w = t >> 6;
  int quad = lane >> 4;

  // stage A: 64 rows x 256 bf16 (direct uint4 copies, XOR-swizzled)
#pragma unroll
  for (int i = 0; i < 8; ++i) {
    int idx = i * 256 + t;  // 0..2047 uint4s
    int m = idx >> 5;
    int kb = idx & 31;
    uint4 u = make_uint4(0, 0, 0, 0);
    if (n0 + m < N_NODES) u = ((const uint4*)(h2h + (size_t)(n0 + m) * 256))[kb];
    *(uint4*)&ldsA[m * 256 + ((kb ^ (m & 7)) << 3)] = u;
  }
  // stage B: 1536 uint4
  const uint4* Bg = (const uint4*)W2f;
#pragma unroll
  for (int i = 0; i < 6; ++i) ((uint4*)ldsB)[i * 256 + t] = Bg[i * 256 + t];
  __syncthreads();

  f32x4 acc[3];
#pragma unroll
  for (int nt = 0; nt < 3; ++nt) acc[nt] = 0.f;

#pragma unroll
  for (int ks = 0; ks < 8; ++ks) {
    int m = w * 16 + (lane & 15);
    int kb = ks * 4 + quad;
    bf16x8 af = *(const bf16x8*)&ldsA[m * 256 + ((kb ^ (m & 7)) << 3)];
#pragma unroll
    for (int nt = 0; nt < 3; ++nt) {
      bf16x8 bf = *(const bf16x8*)&ldsB[((nt * 8 + ks) * 64 + lane) * 8];
      acc[nt] = __builtin_amdgcn_mfma_f32_16x16x32_bf16(af, bf, acc[nt], 0, 0, 0);
    }
  }
  __syncthreads();  // all B reads done before C overwrites

#pragma unroll
  for (int nt = 0; nt < 3; ++nt)
#pragma unroll
    for (int r = 0; r < 4; ++r)
      ldsC[(w * 16 + quad * 4 + r) * 48 + nt * 16 + (lane & 15)] = acc[nt][r];
  __syncthreads();

  // feat2p write: 64 rows x 48 cols (col 47 = 0 from zero-padded B), float4 aligned
#pragma unroll
  for (int i = 0; i < 3; ++i) {
    int idx = i * 256 + t;  // 0..767 float4s
    int row = idx / 12;
    int c4 = idx - row * 12;
    int grow = n0 + row;
    if (grow < N_NODES)
      *(float4*)&feat2p[(size_t)grow * 48 + c4 * 4] = *(const float4*)&ldsC[row * 48 + c4 * 4];
  }
}

// ---------------- Layer 2 aggregate + fused scores + log_softmax ----------------
// Phase A: one lrelu_exp per edge across 256 threads -> LDS.
// Phase B: 4 waves aggregate. Lane 0's esum IS the wave partial (no reduce!).
__global__ __launch_bounds__(256) void agg2_kernel(
    const int* __restrict__ src_csr, const int* __restrict__ offsets,
    const float* __restrict__ feat2p, const float* __restrict__ el2,
    const float* __restrict__ er2, float* __restrict__ out) {
  __shared__ float lds_s[256];
  __shared__ float ldsacc[4][48];
  __shared__ float ldssum[4];
  int n = blockIdx.x;
  int t = threadIdx.x;
  int w = t >> 6;
  int lane = t & 63;
  int off = offsets[n];
  int deg = offsets[n + 1] - off;
  float ern = er2[n];

  float acc = 0.f;
  float esum = 0.f;
  for (int c0 = 0; c0 < deg; c0 += 256) {
    int cnt = min(256, deg - c0);
    if (t < cnt) lds_s[t] = lrelu_exp(el2[src_csr[off + c0 + t]] + ern);
    __syncthreads();
    for (int j = w; j < cnt; j += 4) {
      int sn = src_csr[off + c0 + j];  // broadcast
      float a = lds_s[j];
      float f = (lane < 48) ? feat2p[(size_t)sn * 48 + lane] : 0.f;
      acc += a * f;
      esum += a;
    }
    __syncthreads();
  }
  if (lane < OUT_FEATS) ldsacc[w][lane] = acc;
  if (lane == 0) ldssum[w] = esum;  // all lanes identical; take lane 0 (no reduce!)
  __syncthreads();

  if (t < 64) {
    float denom = ldssum[0] + ldssum[1] + ldssum[2] + ldssum[3];
    float inv = 1.f / fmaxf(denom, 1e-9f);
    float logits = 0.f;
    if (t < OUT_FEATS)
      logits = (ldsacc[0][t] + ldsacc[1][t] + ldsacc[2][t] + ldsacc[3][t]) * inv;
    float v = (t < OUT_FEATS) ? logits : -INFINITY;
    float mx = wave_reduce_max(v);
    float ex = (t < OUT_FEATS) ? expf(logits - mx) : 0.f;
    float s = wave_reduce_sum(ex);
    if (t < OUT_FEATS) out[n * OUT_FEATS + t] = logits - mx - logf(s);
  }
}

extern "C" void kernel_launch(void* const* d_in, const int* in_sizes, int n_in,
                              void* d_out, int out_size, void* d_ws, size_t ws_size,
                              hipStream_t stream) {
  const float* features = (const float*)d_in[0];
  const int* src = (const int*)d_in[1];
  const int* dst = (const int*)d_in[2];
  const float* W1 = (const float*)d_in[3];
  const float* al1 = (const float*)d_in[4];
  const float* ar1 = (const float*)d_in[5];
  const float* W2 = (const float*)d_in[6];
  const float* al2 = (const float*)d_in[7];
  const float* ar2 = (const float*)d_in[8];
  float* out = (float*)d_out;

  char* ws = (char*)d_ws;
  size_t o = 0;
  auto alloc = [&](size_t bytes) {
    void* p = ws + o;
    o = (o + bytes + 255) & ~(size_t)255;
    return p;
  };
  unsigned short* feat1h = (unsigned short*)alloc((size_t)N_NODES * 256 * 2);
  unsigned short* h2h = (unsigned short*)alloc((size_t)N_NODES * 256 * 2);
  float* el1 = (float*)alloc((size_t)N_NODES * 4 * 4);
  float* er1 = (float*)alloc((size_t)N_NODES * 4 * 4);
  float* feat2p = (float*)alloc((size_t)N_NODES * 48 * 4);
  float* el2v = (float*)alloc((size_t)N_NODES * 4);
  float* er2v = (float*)alloc((size_t)N_NODES * 4);
  float* escore1_csr = (float*)alloc((size_t)N_EDGES * 4 * 4);
  unsigned short* W1f = (unsigned short*)alloc((size_t)256 * 256 * 2);
  unsigned short* W2f = (unsigned short*)alloc((size_t)256 * 48 * 2);
  float* wa = (float*)alloc(256 * 4);
  float* wb = (float*)alloc(256 * 4);
  int* deg = (int*)alloc((size_t)N_NODES * 4);
  int* cursor = (int*)alloc((size_t)N_NODES * 4);
  int* offsets = (int*)alloc((size_t)(N_NODES + 1) * 4);
  int* src_csr = (int*)alloc((size_t)N_EDGES * 4);

  hipMemsetAsync(deg, 0, (size_t)N_NODES * 4, stream);

  prep_kernel<<<1555, 256, 0, stream>>>(dst, deg, W1, W1f, W2, W2f, al2, ar2, wa, wb);
  scan_offsets_kernel<<<1, 256, 0, stream>>>(deg, offsets, cursor);
  gemm1_kernel<<<(N_NODES + 31) / 32, 256, 0, stream>>>(features, W1f, al1, ar1, feat1h, el1,
                                                        er1);
  fill_escore1_kernel<<<(N_EDGES + 255) / 256, 256, 0, stream>>>(src, dst, cursor, src_csr,
                                                                 el1, er1, escore1_csr);
  agg1_kernel<<<N_NODES, 256, 0, stream>>>(src_csr, offsets, feat1h, escore1_csr, wa, wb, h2h,
                                           el2v, er2v);
  gemm2_kernel<<<(N_NODES + 63) / 64, 256, 0, stream>>>(h2h, W2f, feat2p);
  agg2_kernel<<<N_NODES, 256, 0, stream>>>(src_csr, offsets, feat2p, el2v, er2v, out);
}

// Round 10
// 200.311 us; speedup vs baseline: 1.4534x; 1.1002x over previous
//
#include <hip/hip_runtime.h>
#include <math.h>

#define N_NODES 10000
#define N_EDGES 320000
#define IN_FEATS 256
#define N_HEADS 4
#define N_UNITS 64
#define OUT_FEATS 47
#define NEG_SLOPE 0.2f

typedef __attribute__((ext_vector_type(8))) short bf16x8;
typedef __attribute__((ext_vector_type(4))) float f32x4;

__device__ __forceinline__ float wave_reduce_sum(float v) {
#pragma unroll
  for (int s = 32; s > 0; s >>= 1) v += __shfl_down(v, s, 64);
  return __shfl(v, 0, 64);
}
__device__ __forceinline__ float wave_reduce_max(float v) {
#pragma unroll
  for (int s = 32; s > 0; s >>= 1) v = fmaxf(v, __shfl_down(v, s, 64));
  return __shfl(v, 0, 64);
}

__device__ __forceinline__ float lrelu_exp(float s) {
  s = (s > 0.f) ? s : NEG_SLOPE * s;
  return expf(s);
}

// fp32 -> bf16 round-to-nearest-even
__device__ __forceinline__ unsigned f2bf(float f) {
  unsigned u = __float_as_uint(f);
  return (u + 0x7FFFu + ((u >> 16) & 1u)) >> 16;
}

// ---------------- fused prep: deg count + W1/W2 packing + wa/wb ----------------
// blocks [0,1250): count_deg; [1250,1506): W1 pack; [1506,1554): W2 pack;
// 1554: wa = W2 @ al2, wb = W2 @ ar2 (for agg1's fused el2/er2).
__global__ __launch_bounds__(256) void prep_kernel(
    const int* __restrict__ dst, int* __restrict__ deg,
    const float* __restrict__ W1, unsigned short* __restrict__ W1f,
    const float* __restrict__ W2, unsigned short* __restrict__ W2f,
    const float* __restrict__ al2, const float* __restrict__ ar2,
    float* __restrict__ wa, float* __restrict__ wb) {
  int b = blockIdx.x;
  int t = threadIdx.x;
  if (b < 1250) {
    int e = b * 256 + t;
    if (e < N_EDGES) atomicAdd(&deg[dst[e]], 1);
  } else if (b < 1250 + 256) {
    int o = (b - 1250) * 256 + t;  // 0..65535
    int j = o & 7;
    int lane = (o >> 3) & 63;
    int r = o >> 9;
    int ks = r & 7;
    int ntg = r >> 3;
    int k = ks * 32 + (lane >> 4) * 8 + j;
    int n = ntg * 16 + (lane & 15);
    W1f[o] = (unsigned short)f2bf(W1[k * 256 + n]);
  } else if (b < 1554) {
    int o = (b - 1506) * 256 + t;  // 0..12287
    int j = o & 7;
    int lane = (o >> 3) & 63;
    int r = o >> 9;  // 0..23
    int ks = r & 7;
    int ntg = r >> 3;  // 0..2
    int k = ks * 32 + (lane >> 4) * 8 + j;
    int n = ntg * 16 + (lane & 15);
    W2f[o] = (n < OUT_FEATS) ? (unsigned short)f2bf(W2[k * OUT_FEATS + n]) : 0;
  } else {
    float a = 0.f, r = 0.f;
    for (int c = 0; c < OUT_FEATS; ++c) {
      float w = W2[t * OUT_FEATS + c];
      a += w * al2[c];
      r += w * ar2[c];
    }
    wa[t] = a;
    wb[t] = r;
  }
}

// CSR fill + layer-1 edge exp-scores, CSR-ordered.
__global__ void fill_escore1_kernel(const int* __restrict__ src, const int* __restrict__ dst,
                                    int* __restrict__ cursor, int* __restrict__ src_csr,
                                    const float* __restrict__ el1, const float* __restrict__ er1,
                                    float* __restrict__ escore1_csr) {
  int e = blockIdx.x * blockDim.x + threadIdx.x;
  if (e >= N_EDGES) return;
  int d = dst[e];
  int sn = src[e];
  int p = atomicAdd(&cursor[d], 1);
  src_csr[p] = sn;
  float4 el = ((const float4*)el1)[sn];
  float4 er = ((const float4*)er1)[d];
  float4 sc;
  sc.x = lrelu_exp(el.x + er.x);
  sc.y = lrelu_exp(el.y + er.y);
  sc.z = lrelu_exp(el.z + er.z);
  sc.w = lrelu_exp(el.w + er.w);
  ((float4*)escore1_csr)[p] = sc;
}

// ---------------- Layer 1 GEMM (MFMA bf16) + fused scan (block 313) ----------------
// Blocks 0..312: feat1h = features @ W1 tiles (32 rows each), fused el1/er1.
// Block 313: exclusive-scan deg -> offsets/cursor (independent of GEMM).
__global__ __launch_bounds__(256) void gemm1_scan_kernel(
    const float* __restrict__ features, const unsigned short* __restrict__ W1f,
    const float* __restrict__ al1, const float* __restrict__ ar1,
    unsigned short* __restrict__ feat1h, float* __restrict__ el1, float* __restrict__ er1,
    const int* __restrict__ deg, int* __restrict__ offsets, int* __restrict__ cursor) {
  __shared__ __align__(16) char smem[49152];
  int t = threadIdx.x;

  if (blockIdx.x == 313) {  // ---- scan path ----
    int* partial = (int*)smem;
    const int chunk = (N_NODES + 255) / 256;  // 40
    int start = t * chunk;
    int end = min(start + chunk, N_NODES);
    int sum = 0;
    for (int i = start; i < end; ++i) sum += deg[i];
    partial[t] = sum;
    __syncthreads();
    for (int s = 1; s < 256; s <<= 1) {
      int v = (t >= s) ? partial[t - s] : 0;
      __syncthreads();
      partial[t] += v;
      __syncthreads();
    }
    int base = (t == 0) ? 0 : partial[t - 1];
    for (int i = start; i < end; ++i) {
      offsets[i] = base;
      cursor[i] = base;
      base += deg[i];
    }
    if (t == 0) offsets[N_NODES] = partial[255];
    return;
  }

  // ---- GEMM path ----
  unsigned short* ldsA = (unsigned short*)smem;                    // 16 KB
  unsigned short* ldsBbuf[2] = {(unsigned short*)(smem + 16384),
                                (unsigned short*)(smem + 32768)};  // 2 x 16 KB
  float* ldsC = (float*)(smem + 16384);                            // 32 KB (reuse B)

  int n0 = blockIdx.x * 32;
  int lane = t & 63;
  int w = t >> 6;
  int quad = lane >> 4;

  const float4* feat4 = (const float4*)features;
#pragma unroll
  for (int i = 0; i < 8; ++i) {
    int idx = i * 256 + t;
    int m = idx >> 6;
    int kb4 = idx & 63;
    float4 f = make_float4(0.f, 0.f, 0.f, 0.f);
    if (n0 + m < N_NODES) f = feat4[(size_t)(n0 + m) * 64 + kb4];
    unsigned u0 = f2bf(f.x) | (f2bf(f.y) << 16);
    unsigned u1 = f2bf(f.z) | (f2bf(f.w) << 16);
    int kb = kb4 >> 1;
    int di = m * 256 + ((kb ^ (m & 7)) << 3) + ((kb4 & 1) << 2);
    *(uint2*)&ldsA[di] = make_uint2(u0, u1);
  }

  const uint4* W1f4 = (const uint4*)W1f;
  uint4 pb[4];
#pragma unroll
  for (int it = 0; it < 4; ++it) {
    int ci = it * 256 + t;
    pb[it] = W1f4[((ci >> 6) * 8 + 0) * 64 + (ci & 63)];
  }
#pragma unroll
  for (int it = 0; it < 4; ++it) ((uint4*)ldsBbuf[0])[it * 256 + t] = pb[it];
  __syncthreads();

  f32x4 acc[2][4];
#pragma unroll
  for (int mt = 0; mt < 2; ++mt)
#pragma unroll
    for (int nt = 0; nt < 4; ++nt) acc[mt][nt] = 0.f;

  for (int ks = 0; ks < 8; ++ks) {
    if (ks < 7) {
#pragma unroll
      for (int it = 0; it < 4; ++it) {
        int ci = it * 256 + t;
        pb[it] = W1f4[((ci >> 6) * 8 + ks + 1) * 64 + (ci & 63)];
      }
    }
    unsigned short* B = ldsBbuf[ks & 1];
    bf16x8 af[2];
#pragma unroll
    for (int mt = 0; mt < 2; ++mt) {
      int m = mt * 16 + (lane & 15);
      int kb = ks * 4 + quad;
      af[mt] = *(const bf16x8*)&ldsA[m * 256 + ((kb ^ (m & 7)) << 3)];
    }
#pragma unroll
    for (int nt = 0; nt < 4; ++nt) {
      bf16x8 bf = *(const bf16x8*)&B[((w * 4 + nt) * 64 + lane) * 8];
#pragma unroll
      for (int mt = 0; mt < 2; ++mt)
        acc[mt][nt] = __builtin_amdgcn_mfma_f32_16x16x32_bf16(af[mt], bf, acc[mt][nt], 0, 0, 0);
    }
    if (ks < 7) {
      unsigned short* Bn = ldsBbuf[(ks + 1) & 1];
#pragma unroll
      for (int it = 0; it < 4; ++it) ((uint4*)Bn)[it * 256 + t] = pb[it];
    }
    __syncthreads();
  }

#pragma unroll
  for (int mt = 0; mt < 2; ++mt)
#pragma unroll
    for (int nt = 0; nt < 4; ++nt)
#pragma unroll
      for (int r = 0; r < 4; ++r)
        ldsC[(mt * 16 + quad * 4 + r) * 256 + w * 64 + nt * 16 + (lane & 15)] = acc[mt][nt][r];
  __syncthreads();

  int c = lane * 4;
  int r0 = w * 8;
  float4 alv = ((const float4*)al1)[lane];
  float4 arv = ((const float4*)ar1)[lane];
#pragma unroll
  for (int i = 0; i < 8; ++i) {
    int rl = r0 + i;
    int row = n0 + rl;
    float4 a = *(const float4*)&ldsC[rl * 256 + c];
    bool valid = row < N_NODES;
    if (valid) {
      unsigned p0 = f2bf(a.x) | (f2bf(a.y) << 16);
      unsigned p1 = f2bf(a.z) | (f2bf(a.w) << 16);
      *(uint2*)&feat1h[(size_t)row * 256 + c] = make_uint2(p0, p1);
    }
    float el = a.x * alv.x + a.y * alv.y + a.z * alv.z + a.w * alv.w;
    float er = a.x * arv.x + a.y * arv.y + a.z * arv.z + a.w * arv.w;
#pragma unroll
    for (int s = 8; s > 0; s >>= 1) {
      el += __shfl_down(el, s, 16);
      er += __shfl_down(er, s, 16);
    }
    if ((lane & 15) == 0 && valid) {
      el1[row * 4 + (lane >> 4)] = el;
      er1[row * 4 + (lane >> 4)] = er;
    }
  }
}

// ---------------- Layer 1 aggregate: 2 edges/wave-iter, bf16 h2 out, fused el2/er2 ----
__global__ __launch_bounds__(256) void agg1_kernel(
    const int* __restrict__ src_csr, const int* __restrict__ offsets,
    const unsigned short* __restrict__ feat1h, const float* __restrict__ escore1_csr,
    const float* __restrict__ wa, const float* __restrict__ wb,
    unsigned short* __restrict__ h2h, float* __restrict__ el2, float* __restrict__ er2) {
  __shared__ float ldsacc[4][256];
  __shared__ float ldssum[4][4];
  __shared__ float ldse[4], ldsr[4];
  int n = blockIdx.x;
  int t = threadIdx.x;
  int w = t >> 6;
  int lane = t & 63;
  int half = lane >> 5;
  int hl = lane & 31;
  int off = offsets[n];
  int deg = offsets[n + 1] - off;
  int head = hl >> 3;

  float acc[8];
#pragma unroll
  for (int r = 0; r < 8; ++r) acc[r] = 0.f;
  float4 esum = {0.f, 0.f, 0.f, 0.f};

  for (int p = w * 2 + half; p < deg; p += 8) {
    int sn = src_csr[off + p];
    float4 a4 = ((const float4*)escore1_csr)[off + p];
    uint4 u = *(const uint4*)&feat1h[(size_t)sn * 256 + hl * 8];
    float aw = (head == 0) ? a4.x : (head == 1) ? a4.y : (head == 2) ? a4.z : a4.w;
    acc[0] += aw * __uint_as_float(u.x << 16);
    acc[1] += aw * __uint_as_float(u.x & 0xFFFF0000u);
    acc[2] += aw * __uint_as_float(u.y << 16);
    acc[3] += aw * __uint_as_float(u.y & 0xFFFF0000u);
    acc[4] += aw * __uint_as_float(u.z << 16);
    acc[5] += aw * __uint_as_float(u.z & 0xFFFF0000u);
    acc[6] += aw * __uint_as_float(u.w << 16);
    acc[7] += aw * __uint_as_float(u.w & 0xFFFF0000u);
    esum.x += a4.x;
    esum.y += a4.y;
    esum.z += a4.z;
    esum.w += a4.w;
  }
#pragma unroll
  for (int r = 0; r < 8; ++r) acc[r] += __shfl_down(acc[r], 32, 64);
  esum.x += __shfl_down(esum.x, 32, 64);
  esum.y += __shfl_down(esum.y, 32, 64);
  esum.z += __shfl_down(esum.z, 32, 64);
  esum.w += __shfl_down(esum.w, 32, 64);
  if (half == 0) {
    *(float4*)&ldsacc[w][hl * 8] = make_float4(acc[0], acc[1], acc[2], acc[3]);
    *(float4*)&ldsacc[w][hl * 8 + 4] = make_float4(acc[4], acc[5], acc[6], acc[7]);
  }
  if (lane == 0) *(float4*)&ldssum[w][0] = esum;
  __syncthreads();

  float tot = ldsacc[0][t] + ldsacc[1][t] + ldsacc[2][t] + ldsacc[3][t];
  int h = t >> 6;
  float denom = ldssum[0][h] + ldssum[1][h] + ldssum[2][h] + ldssum[3][h];
  float val = tot / fmaxf(denom, 1e-9f);
  val = (val > 0.f) ? val : expm1f(val);  // ELU

  float elp = val * wa[t];
  float erp = val * wb[t];
#pragma unroll
  for (int s = 32; s > 0; s >>= 1) {
    elp += __shfl_down(elp, s, 64);
    erp += __shfl_down(erp, s, 64);
  }
  if (lane == 0) {
    ldse[w] = elp;
    ldsr[w] = erp;
  }
  float vhi = __shfl_down(val, 1, 64);
  if (!(t & 1)) *(unsigned*)&h2h[(size_t)n * 256 + t] = f2bf(val) | (f2bf(vhi) << 16);
  __syncthreads();
  if (t == 0) {
    el2[n] = ldse[0] + ldse[1] + ldse[2] + ldse[3];
    er2[n] = ldsr[0] + ldsr[1] + ldsr[2] + ldsr[3];
  }
}

// ---------------- Layer 2 GEMM (MFMA bf16): feat2ph(bf16, 48-padded) = h2h @ W2 ------
__global__ __launch_bounds__(256) void gemm2_kernel(
    const unsigned short* __restrict__ h2h, const unsigned short* __restrict__ W2f,
    unsigned short* __restrict__ feat2ph) {
  __shared__ __align__(16) char smem[32768 + 24576];
  unsigned short* ldsA = (unsigned short*)smem;            // 32 KB
  unsigned short* ldsB = (unsigned short*)(smem + 32768);  // 24 KB
  float* ldsC = (float*)(smem + 32768);                    // 12 KB (reuse B)

  int t = threadIdx.x;
  int n0 = blockIdx.x * 64;
  int lane = t & 63;
  int w = t >> 6;
  int quad = lane >> 4;

#pragma unroll
  for (int i = 0; i < 8; ++i) {
    int idx = i * 256 + t;  // 0..2047 uint4s
    int m = idx >> 5;
    int kb = idx & 31;
    uint4 u = make_uint4(0, 0, 0, 0);
    if (n0 + m < N_NODES) u = ((const uint4*)(h2h + (size_t)(n0 + m) * 256))[kb];
    *(uint4*)&ldsA[m * 256 + ((kb ^ (m & 7)) << 3)] = u;
  }
  const uint4* Bg = (const uint4*)W2f;
#pragma unroll
  for (int i = 0; i < 6; ++i) ((uint4*)ldsB)[i * 256 + t] = Bg[i * 256 + t];
  __syncthreads();

  f32x4 acc[3];
#pragma unroll
  for (int nt = 0; nt < 3; ++nt) acc[nt] = 0.f;

#pragma unroll
  for (int ks = 0; ks < 8; ++ks) {
    int m = w * 16 + (lane & 15);
    int kb = ks * 4 + quad;
    bf16x8 af = *(const bf16x8*)&ldsA[m * 256 + ((kb ^ (m & 7)) << 3)];
#pragma unroll
    for (int nt = 0; nt < 3; ++nt) {
      bf16x8 bf = *(const bf16x8*)&ldsB[((nt * 8 + ks) * 64 + lane) * 8];
      acc[nt] = __builtin_amdgcn_mfma_f32_16x16x32_bf16(af, bf, acc[nt], 0, 0, 0);
    }
  }
  __syncthreads();  // all B reads done before C overwrites

#pragma unroll
  for (int nt = 0; nt < 3; ++nt)
#pragma unroll
    for (int r = 0; r < 4; ++r)
      ldsC[(w * 16 + quad * 4 + r) * 48 + nt * 16 + (lane & 15)] = acc[nt][r];
  __syncthreads();

  // feat2ph write: 64 rows x 24 packed uints (48 bf16 cols, col 47 = 0)
#pragma unroll
  for (int i = 0; i < 6; ++i) {
    int idx = i * 256 + t;  // 0..1535
    int row = idx / 24;
    int c2 = idx - row * 24;
    int grow = n0 + row;
    if (grow < N_NODES) {
      unsigned u = f2bf(ldsC[row * 48 + c2 * 2]) | (f2bf(ldsC[row * 48 + c2 * 2 + 1]) << 16);
      ((unsigned*)feat2ph)[(size_t)grow * 24 + c2] = u;
    }
  }
}

// ---------------- Layer 2 aggregate + fused scores + log_softmax ----------------
// Phase A: one lrelu_exp per edge across 256 threads -> LDS.
// Phase B: half-wave per edge (2 edges/wave-iter); lanes 0..23 of each half
// hold cols 2hl, 2hl+1 (bf16 gather, 96 B/edge). Halves combine via
// shfl_down(32); lane 0's esum IS the wave partial (no wave-reduce!).
__global__ __launch_bounds__(256) void agg2_kernel(
    const int* __restrict__ src_csr, const int* __restrict__ offsets,
    const unsigned short* __restrict__ feat2ph, const float* __restrict__ el2,
    const float* __restrict__ er2, float* __restrict__ out) {
  __shared__ float lds_s[256];
  __shared__ float ldsacc[4][48];
  __shared__ float ldssum[4];
  int n = blockIdx.x;
  int t = threadIdx.x;
  int w = t >> 6;
  int lane = t & 63;
  int half = lane >> 5;
  int hl = lane & 31;
  int off = offsets[n];
  int deg = offsets[n + 1] - off;
  float ern = er2[n];

  float a0 = 0.f, a1 = 0.f;
  float esum = 0.f;
  for (int c0 = 0; c0 < deg; c0 += 256) {
    int cnt = min(256, deg - c0);
    if (t < cnt) lds_s[t] = lrelu_exp(el2[src_csr[off + c0 + t]] + ern);
    __syncthreads();
    for (int p = w * 2 + half; p < cnt; p += 8) {
      int sn = src_csr[off + c0 + p];  // half-uniform broadcast
      float a = lds_s[p];
      if (hl < 24) {
        unsigned u = ((const unsigned*)feat2ph)[(size_t)sn * 24 + hl];
        a0 += a * __uint_as_float(u << 16);
        a1 += a * __uint_as_float(u & 0xFFFF0000u);
      }
      esum += a;
    }
    __syncthreads();
  }
  a0 += __shfl_down(a0, 32, 64);
  a1 += __shfl_down(a1, 32, 64);
  esum += __shfl_down(esum, 32, 64);
  if (half == 0 && hl < 24) {
    ldsacc[w][hl * 2] = a0;
    ldsacc[w][hl * 2 + 1] = a1;
  }
  if (lane == 0) ldssum[w] = esum;
  __syncthreads();

  if (t < 64) {
    float denom = ldssum[0] + ldssum[1] + ldssum[2] + ldssum[3];
    float inv = 1.f / fmaxf(denom, 1e-9f);
    float logits = 0.f;
    if (t < OUT_FEATS)
      logits = (ldsacc[0][t] + ldsacc[1][t] + ldsacc[2][t] + ldsacc[3][t]) * inv;
    float v = (t < OUT_FEATS) ? logits : -INFINITY;
    float mx = wave_reduce_max(v);
    float ex = (t < OUT_FEATS) ? expf(logits - mx) : 0.f;
    float s = wave_reduce_sum(ex);
    if (t < OUT_FEATS) out[n * OUT_FEATS + t] = logits - mx - logf(s);
  }
}

extern "C" void kernel_launch(void* const* d_in, const int* in_sizes, int n_in,
                              void* d_out, int out_size, void* d_ws, size_t ws_size,
                              hipStream_t stream) {
  const float* features = (const float*)d_in[0];
  const int* src = (const int*)d_in[1];
  const int* dst = (const int*)d_in[2];
  const float* W1 = (const float*)d_in[3];
  const float* al1 = (const float*)d_in[4];
  const float* ar1 = (const float*)d_in[5];
  const float* W2 = (const float*)d_in[6];
  const float* al2 = (const float*)d_in[7];
  const float* ar2 = (const float*)d_in[8];
  float* out = (float*)d_out;

  char* ws = (char*)d_ws;
  size_t o = 0;
  auto alloc = [&](size_t bytes) {
    void* p = ws + o;
    o = (o + bytes + 255) & ~(size_t)255;
    return p;
  };
  unsigned short* feat1h = (unsigned short*)alloc((size_t)N_NODES * 256 * 2);
  unsigned short* h2h = (unsigned short*)alloc((size_t)N_NODES * 256 * 2);
  float* el1 = (float*)alloc((size_t)N_NODES * 4 * 4);
  float* er1 = (float*)alloc((size_t)N_NODES * 4 * 4);
  unsigned short* feat2ph = (unsigned short*)alloc((size_t)N_NODES * 48 * 2);
  float* el2v = (float*)alloc((size_t)N_NODES * 4);
  float* er2v = (float*)alloc((size_t)N_NODES * 4);
  float* escore1_csr = (float*)alloc((size_t)N_EDGES * 4 * 4);
  unsigned short* W1f = (unsigned short*)alloc((size_t)256 * 256 * 2);
  unsigned short* W2f = (unsigned short*)alloc((size_t)256 * 48 * 2);
  float* wa = (float*)alloc(256 * 4);
  float* wb = (float*)alloc(256 * 4);
  int* deg = (int*)alloc((size_t)N_NODES * 4);
  int* cursor = (int*)alloc((size_t)N_NODES * 4);
  int* offsets = (int*)alloc((size_t)(N_NODES + 1) * 4);
  int* src_csr = (int*)alloc((size_t)N_EDGES * 4);

  hipMemsetAsync(deg, 0, (size_t)N_NODES * 4, stream);

  prep_kernel<<<1555, 256, 0, stream>>>(dst, deg, W1, W1f, W2, W2f, al2, ar2, wa, wb);
  gemm1_scan_kernel<<<314, 256, 0, stream>>>(features, W1f, al1, ar1, feat1h, el1, er1, deg,
                                             offsets, cursor);
  fill_escore1_kernel<<<(N_EDGES + 255) / 256, 256, 0, stream>>>(src, dst, cursor, src_csr,
                                                                 el1, er1, escore1_csr);
  agg1_kernel<<<N_NODES, 256, 0, stream>>>(src_csr, offsets, feat1h, escore1_csr, wa, wb, h2h,
                                           el2v, er2v);
  gemm2_kernel<<<(N_NODES + 63) / 64, 256, 0, stream>>>(h2h, W2f, feat2ph);
  agg2_kernel<<<N_NODES, 256, 0, stream>>>(src_csr, offsets, feat2ph, el2v, er2v, out);
}

// Round 11
// 198.174 us; speedup vs baseline: 1.4690x; 1.0108x over previous
//
#include <hip/hip_runtime.h>
#include <math.h>

#define N_NODES 10000
#define N_EDGES 320000
#define IN_FEATS 256
#define N_HEADS 4
#define N_UNITS 64
#define OUT_FEATS 47
#define NEG_SLOPE 0.2f

typedef __attribute__((ext_vector_type(8))) short bf16x8;
typedef __attribute__((ext_vector_type(4))) float f32x4;

__device__ __forceinline__ float wave_reduce_sum(float v) {
#pragma unroll
  for (int s = 32; s > 0; s >>= 1) v += __shfl_down(v, s, 64);
  return __shfl(v, 0, 64);
}
__device__ __forceinline__ float wave_reduce_max(float v) {
#pragma unroll
  for (int s = 32; s > 0; s >>= 1) v = fmaxf(v, __shfl_down(v, s, 64));
  return __shfl(v, 0, 64);
}

__device__ __forceinline__ float lrelu_exp(float s) {
  s = (s > 0.f) ? s : NEG_SLOPE * s;
  return expf(s);
}

// fp32 -> bf16 round-to-nearest-even
__device__ __forceinline__ unsigned f2bf(float f) {
  unsigned u = __float_as_uint(f);
  return (u + 0x7FFFu + ((u >> 16) & 1u)) >> 16;
}

// ---------------- fused prep: deg count + W1/W2 packing + wa/wb ----------------
__global__ __launch_bounds__(256) void prep_kernel(
    const int* __restrict__ dst, int* __restrict__ deg,
    const float* __restrict__ W1, unsigned short* __restrict__ W1f,
    const float* __restrict__ W2, unsigned short* __restrict__ W2f,
    const float* __restrict__ al2, const float* __restrict__ ar2,
    float* __restrict__ wa, float* __restrict__ wb) {
  int b = blockIdx.x;
  int t = threadIdx.x;
  if (b < 1250) {
    int e = b * 256 + t;
    if (e < N_EDGES) atomicAdd(&deg[dst[e]], 1);
  } else if (b < 1250 + 256) {
    int o = (b - 1250) * 256 + t;  // 0..65535
    int j = o & 7;
    int lane = (o >> 3) & 63;
    int r = o >> 9;
    int ks = r & 7;
    int ntg = r >> 3;
    int k = ks * 32 + (lane >> 4) * 8 + j;
    int n = ntg * 16 + (lane & 15);
    W1f[o] = (unsigned short)f2bf(W1[k * 256 + n]);
  } else if (b < 1554) {
    int o = (b - 1506) * 256 + t;  // 0..12287
    int j = o & 7;
    int lane = (o >> 3) & 63;
    int r = o >> 9;  // 0..23
    int ks = r & 7;
    int ntg = r >> 3;  // 0..2
    int k = ks * 32 + (lane >> 4) * 8 + j;
    int n = ntg * 16 + (lane & 15);
    W2f[o] = (n < OUT_FEATS) ? (unsigned short)f2bf(W2[k * OUT_FEATS + n]) : 0;
  } else {
    float a = 0.f, r = 0.f;
    for (int c = 0; c < OUT_FEATS; ++c) {
      float w = W2[t * OUT_FEATS + c];
      a += w * al2[c];
      r += w * ar2[c];
    }
    wa[t] = a;
    wb[t] = r;
  }
}

// CSR fill: src_csr only (scores now computed in-block inside agg1).
__global__ void fill_kernel(const int* __restrict__ src, const int* __restrict__ dst,
                            int* __restrict__ cursor, int* __restrict__ src_csr) {
  int e = blockIdx.x * blockDim.x + threadIdx.x;
  if (e >= N_EDGES) return;
  int p = atomicAdd(&cursor[dst[e]], 1);
  src_csr[p] = src[e];
}

// ---------------- Layer 1 GEMM (MFMA bf16) + fused scan (block 313) ----------------
__global__ __launch_bounds__(256) void gemm1_scan_kernel(
    const float* __restrict__ features, const unsigned short* __restrict__ W1f,
    const float* __restrict__ al1, const float* __restrict__ ar1,
    unsigned short* __restrict__ feat1h, float* __restrict__ el1, float* __restrict__ er1,
    const int* __restrict__ deg, int* __restrict__ offsets, int* __restrict__ cursor) {
  __shared__ __align__(16) char smem[49152];
  int t = threadIdx.x;

  if (blockIdx.x == 313) {  // ---- scan path ----
    int* partial = (int*)smem;
    const int chunk = (N_NODES + 255) / 256;  // 40
    int start = t * chunk;
    int end = min(start + chunk, N_NODES);
    int sum = 0;
    for (int i = start; i < end; ++i) sum += deg[i];
    partial[t] = sum;
    __syncthreads();
    for (int s = 1; s < 256; s <<= 1) {
      int v = (t >= s) ? partial[t - s] : 0;
      __syncthreads();
      partial[t] += v;
      __syncthreads();
    }
    int base = (t == 0) ? 0 : partial[t - 1];
    for (int i = start; i < end; ++i) {
      offsets[i] = base;
      cursor[i] = base;
      base += deg[i];
    }
    if (t == 0) offsets[N_NODES] = partial[255];
    return;
  }

  // ---- GEMM path ----
  unsigned short* ldsA = (unsigned short*)smem;                    // 16 KB
  unsigned short* ldsBbuf[2] = {(unsigned short*)(smem + 16384),
                                (unsigned short*)(smem + 32768)};  // 2 x 16 KB
  float* ldsC = (float*)(smem + 16384);                            // 32 KB (reuse B)

  int n0 = blockIdx.x * 32;
  int lane = t & 63;
  int w = t >> 6;
  int quad = lane >> 4;

  const float4* feat4 = (const float4*)features;
#pragma unroll
  for (int i = 0; i < 8; ++i) {
    int idx = i * 256 + t;
    int m = idx >> 6;
    int kb4 = idx & 63;
    float4 f = make_float4(0.f, 0.f, 0.f, 0.f);
    if (n0 + m < N_NODES) f = feat4[(size_t)(n0 + m) * 64 + kb4];
    unsigned u0 = f2bf(f.x) | (f2bf(f.y) << 16);
    unsigned u1 = f2bf(f.z) | (f2bf(f.w) << 16);
    int kb = kb4 >> 1;
    int di = m * 256 + ((kb ^ (m & 7)) << 3) + ((kb4 & 1) << 2);
    *(uint2*)&ldsA[di] = make_uint2(u0, u1);
  }

  const uint4* W1f4 = (const uint4*)W1f;
  uint4 pb[4];
#pragma unroll
  for (int it = 0; it < 4; ++it) {
    int ci = it * 256 + t;
    pb[it] = W1f4[((ci >> 6) * 8 + 0) * 64 + (ci & 63)];
  }
#pragma unroll
  for (int it = 0; it < 4; ++it) ((uint4*)ldsBbuf[0])[it * 256 + t] = pb[it];
  __syncthreads();

  f32x4 acc[2][4];
#pragma unroll
  for (int mt = 0; mt < 2; ++mt)
#pragma unroll
    for (int nt = 0; nt < 4; ++nt) acc[mt][nt] = 0.f;

  for (int ks = 0; ks < 8; ++ks) {
    if (ks < 7) {
#pragma unroll
      for (int it = 0; it < 4; ++it) {
        int ci = it * 256 + t;
        pb[it] = W1f4[((ci >> 6) * 8 + ks + 1) * 64 + (ci & 63)];
      }
    }
    unsigned short* B = ldsBbuf[ks & 1];
    bf16x8 af[2];
#pragma unroll
    for (int mt = 0; mt < 2; ++mt) {
      int m = mt * 16 + (lane & 15);
      int kb = ks * 4 + quad;
      af[mt] = *(const bf16x8*)&ldsA[m * 256 + ((kb ^ (m & 7)) << 3)];
    }
#pragma unroll
    for (int nt = 0; nt < 4; ++nt) {
      bf16x8 bf = *(const bf16x8*)&B[((w * 4 + nt) * 64 + lane) * 8];
#pragma unroll
      for (int mt = 0; mt < 2; ++mt)
        acc[mt][nt] = __builtin_amdgcn_mfma_f32_16x16x32_bf16(af[mt], bf, acc[mt][nt], 0, 0, 0);
    }
    if (ks < 7) {
      unsigned short* Bn = ldsBbuf[(ks + 1) & 1];
#pragma unroll
      for (int it = 0; it < 4; ++it) ((uint4*)Bn)[it * 256 + t] = pb[it];
    }
    __syncthreads();
  }

#pragma unroll
  for (int mt = 0; mt < 2; ++mt)
#pragma unroll
    for (int nt = 0; nt < 4; ++nt)
#pragma unroll
      for (int r = 0; r < 4; ++r)
        ldsC[(mt * 16 + quad * 4 + r) * 256 + w * 64 + nt * 16 + (lane & 15)] = acc[mt][nt][r];
  __syncthreads();

  int c = lane * 4;
  int r0 = w * 8;
  float4 alv = ((const float4*)al1)[lane];
  float4 arv = ((const float4*)ar1)[lane];
#pragma unroll
  for (int i = 0; i < 8; ++i) {
    int rl = r0 + i;
    int row = n0 + rl;
    float4 a = *(const float4*)&ldsC[rl * 256 + c];
    bool valid = row < N_NODES;
    if (valid) {
      unsigned p0 = f2bf(a.x) | (f2bf(a.y) << 16);
      unsigned p1 = f2bf(a.z) | (f2bf(a.w) << 16);
      *(uint2*)&feat1h[(size_t)row * 256 + c] = make_uint2(p0, p1);
    }
    float el = a.x * alv.x + a.y * alv.y + a.z * alv.z + a.w * alv.w;
    float er = a.x * arv.x + a.y * arv.y + a.z * arv.z + a.w * arv.w;
#pragma unroll
    for (int s = 8; s > 0; s >>= 1) {
      el += __shfl_down(el, s, 16);
      er += __shfl_down(er, s, 16);
    }
    if ((lane & 15) == 0 && valid) {
      el1[row * 4 + (lane >> 4)] = el;
      er1[row * 4 + (lane >> 4)] = er;
    }
  }
}

// ---------------- Layer 1 aggregate: in-block scores + bf16 gather ----------------
// Phase A (per 256-edge tile): thread t computes edge t's 4-head exp-scores into
// LDS (one lrelu_exp per edge per head — edge-parallel, NOT per-lane redundant).
// Phase B: half-wave per edge (2 edges/wave-iter), scores + src ids from LDS.
__global__ __launch_bounds__(256) void agg1_kernel(
    const int* __restrict__ src_csr, const int* __restrict__ offsets,
    const unsigned short* __restrict__ feat1h, const float* __restrict__ el1,
    const float* __restrict__ er1, const float* __restrict__ wa,
    const float* __restrict__ wb, unsigned short* __restrict__ h2h,
    float* __restrict__ el2, float* __restrict__ er2) {
  __shared__ float4 lds_s4[256];
  __shared__ int lds_sn[256];
  __shared__ float ldsacc[4][256];
  __shared__ float ldssum[4][4];
  __shared__ float ldse[4], ldsr[4];
  int n = blockIdx.x;
  int t = threadIdx.x;
  int w = t >> 6;
  int lane = t & 63;
  int half = lane >> 5;
  int hl = lane & 31;
  int off = offsets[n];
  int deg = offsets[n + 1] - off;
  int head = hl >> 3;
  float4 er4 = ((const float4*)er1)[n];

  float acc[8];
#pragma unroll
  for (int r = 0; r < 8; ++r) acc[r] = 0.f;
  float4 esum = {0.f, 0.f, 0.f, 0.f};

  for (int c0 = 0; c0 < deg; c0 += 256) {
    int cnt = min(256, deg - c0);
    if (t < cnt) {
      int sn = src_csr[off + c0 + t];
      float4 el = ((const float4*)el1)[sn];  // 160 KB L2-hot table
      lds_sn[t] = sn;
      lds_s4[t] = make_float4(lrelu_exp(el.x + er4.x), lrelu_exp(el.y + er4.y),
                              lrelu_exp(el.z + er4.z), lrelu_exp(el.w + er4.w));
    }
    __syncthreads();
    for (int p = w * 2 + half; p < cnt; p += 8) {
      int sn = lds_sn[p];    // LDS broadcast
      float4 a4 = lds_s4[p];  // LDS broadcast
      uint4 u = *(const uint4*)&feat1h[(size_t)sn * 256 + hl * 8];  // 512B/edge
      float aw = (head == 0) ? a4.x : (head == 1) ? a4.y : (head == 2) ? a4.z : a4.w;
      acc[0] += aw * __uint_as_float(u.x << 16);
      acc[1] += aw * __uint_as_float(u.x & 0xFFFF0000u);
      acc[2] += aw * __uint_as_float(u.y << 16);
      acc[3] += aw * __uint_as_float(u.y & 0xFFFF0000u);
      acc[4] += aw * __uint_as_float(u.z << 16);
      acc[5] += aw * __uint_as_float(u.z & 0xFFFF0000u);
      acc[6] += aw * __uint_as_float(u.w << 16);
      acc[7] += aw * __uint_as_float(u.w & 0xFFFF0000u);
      esum.x += a4.x;
      esum.y += a4.y;
      esum.z += a4.z;
      esum.w += a4.w;
    }
    __syncthreads();
  }
#pragma unroll
  for (int r = 0; r < 8; ++r) acc[r] += __shfl_down(acc[r], 32, 64);
  esum.x += __shfl_down(esum.x, 32, 64);
  esum.y += __shfl_down(esum.y, 32, 64);
  esum.z += __shfl_down(esum.z, 32, 64);
  esum.w += __shfl_down(esum.w, 32, 64);
  if (half == 0) {
    *(float4*)&ldsacc[w][hl * 8] = make_float4(acc[0], acc[1], acc[2], acc[3]);
    *(float4*)&ldsacc[w][hl * 8 + 4] = make_float4(acc[4], acc[5], acc[6], acc[7]);
  }
  if (lane == 0) *(float4*)&ldssum[w][0] = esum;  // halves combined; lane0 = wave partial
  __syncthreads();

  float tot = ldsacc[0][t] + ldsacc[1][t] + ldsacc[2][t] + ldsacc[3][t];
  int h = t >> 6;
  float denom = ldssum[0][h] + ldssum[1][h] + ldssum[2][h] + ldssum[3][h];
  float val = tot / fmaxf(denom, 1e-9f);
  val = (val > 0.f) ? val : expm1f(val);  // ELU

  float elp = val * wa[t];
  float erp = val * wb[t];
#pragma unroll
  for (int s = 32; s > 0; s >>= 1) {
    elp += __shfl_down(elp, s, 64);
    erp += __shfl_down(erp, s, 64);
  }
  if (lane == 0) {
    ldse[w] = elp;
    ldsr[w] = erp;
  }
  float vhi = __shfl_down(val, 1, 64);
  if (!(t & 1)) *(unsigned*)&h2h[(size_t)n * 256 + t] = f2bf(val) | (f2bf(vhi) << 16);
  __syncthreads();
  if (t == 0) {
    el2[n] = ldse[0] + ldse[1] + ldse[2] + ldse[3];
    er2[n] = ldsr[0] + ldsr[1] + ldsr[2] + ldsr[3];
  }
}

// ---------------- Layer 2 GEMM (MFMA bf16): feat2ph(bf16, 48-padded) = h2h @ W2 ------
__global__ __launch_bounds__(256) void gemm2_kernel(
    const unsigned short* __restrict__ h2h, const unsigned short* __restrict__ W2f,
    unsigned short* __restrict__ feat2ph) {
  __shared__ __align__(16) char smem[32768 + 24576];
  unsigned short* ldsA = (unsigned short*)smem;            // 32 KB
  unsigned short* ldsB = (unsigned short*)(smem + 32768);  // 24 KB
  float* ldsC = (float*)(smem + 32768);                    // 12 KB (reuse B)

  int t = threadIdx.x;
  int n0 = blockIdx.x * 64;
  int lane = t & 63;
  int w = t >> 6;
  int quad = lane >> 4;

#pragma unroll
  for (int i = 0; i < 8; ++i) {
    int idx = i * 256 + t;  // 0..2047 uint4s
    int m = idx >> 5;
    int kb = idx & 31;
    uint4 u = make_uint4(0, 0, 0, 0);
    if (n0 + m < N_NODES) u = ((const uint4*)(h2h + (size_t)(n0 + m) * 256))[kb];
    *(uint4*)&ldsA[m * 256 + ((kb ^ (m & 7)) << 3)] = u;
  }
  const uint4* Bg = (const uint4*)W2f;
#pragma unroll
  for (int i = 0; i < 6; ++i) ((uint4*)ldsB)[i * 256 + t] = Bg[i * 256 + t];
  __syncthreads();

  f32x4 acc[3];
#pragma unroll
  for (int nt = 0; nt < 3; ++nt) acc[nt] = 0.f;

#pragma unroll
  for (int ks = 0; ks < 8; ++ks) {
    int m = w * 16 + (lane & 15);
    int kb = ks * 4 + quad;
    bf16x8 af = *(const bf16x8*)&ldsA[m * 256 + ((kb ^ (m & 7)) << 3)];
#pragma unroll
    for (int nt = 0; nt < 3; ++nt) {
      bf16x8 bf = *(const bf16x8*)&ldsB[((nt * 8 + ks) * 64 + lane) * 8];
      acc[nt] = __builtin_amdgcn_mfma_f32_16x16x32_bf16(af, bf, acc[nt], 0, 0, 0);
    }
  }
  __syncthreads();  // all B reads done before C overwrites

#pragma unroll
  for (int nt = 0; nt < 3; ++nt)
#pragma unroll
    for (int r = 0; r < 4; ++r)
      ldsC[(w * 16 + quad * 4 + r) * 48 + nt * 16 + (lane & 15)] = acc[nt][r];
  __syncthreads();

#pragma unroll
  for (int i = 0; i < 6; ++i) {
    int idx = i * 256 + t;  // 0..1535
    int row = idx / 24;
    int c2 = idx - row * 24;
    int grow = n0 + row;
    if (grow < N_NODES) {
      unsigned u = f2bf(ldsC[row * 48 + c2 * 2]) | (f2bf(ldsC[row * 48 + c2 * 2 + 1]) << 16);
      ((unsigned*)feat2ph)[(size_t)grow * 24 + c2] = u;
    }
  }
}

// ---------------- Layer 2 aggregate + fused scores + log_softmax ----------------
__global__ __launch_bounds__(256) void agg2_kernel(
    const int* __restrict__ src_csr, const int* __restrict__ offsets,
    const unsigned short* __restrict__ feat2ph, const float* __restrict__ el2,
    const float* __restrict__ er2, float* __restrict__ out) {
  __shared__ float lds_s[256];
  __shared__ int lds_sn[256];
  __shared__ float ldsacc[4][48];
  __shared__ float ldssum[4];
  int n = blockIdx.x;
  int t = threadIdx.x;
  int w = t >> 6;
  int lane = t & 63;
  int half = lane >> 5;
  int hl = lane & 31;
  int off = offsets[n];
  int deg = offsets[n + 1] - off;
  float ern = er2[n];

  float a0 = 0.f, a1 = 0.f;
  float esum = 0.f;
  for (int c0 = 0; c0 < deg; c0 += 256) {
    int cnt = min(256, deg - c0);
    if (t < cnt) {
      int sn = src_csr[off + c0 + t];
      lds_sn[t] = sn;
      lds_s[t] = lrelu_exp(el2[sn] + ern);
    }
    __syncthreads();
    for (int p = w * 2 + half; p < cnt; p += 8) {
      int sn = lds_sn[p];
      float a = lds_s[p];
      if (hl < 24) {
        unsigned u = ((const unsigned*)feat2ph)[(size_t)sn * 24 + hl];
        a0 += a * __uint_as_float(u << 16);
        a1 += a * __uint_as_float(u & 0xFFFF0000u);
      }
      esum += a;
    }
    __syncthreads();
  }
  a0 += __shfl_down(a0, 32, 64);
  a1 += __shfl_down(a1, 32, 64);
  esum += __shfl_down(esum, 32, 64);
  if (half == 0 && hl < 24) {
    ldsacc[w][hl * 2] = a0;
    ldsacc[w][hl * 2 + 1] = a1;
  }
  if (lane == 0) ldssum[w] = esum;
  __syncthreads();

  if (t < 64) {
    float denom = ldssum[0] + ldssum[1] + ldssum[2] + ldssum[3];
    float inv = 1.f / fmaxf(denom, 1e-9f);
    float logits = 0.f;
    if (t < OUT_FEATS)
      logits = (ldsacc[0][t] + ldsacc[1][t] + ldsacc[2][t] + ldsacc[3][t]) * inv;
    float v = (t < OUT_FEATS) ? logits : -INFINITY;
    float mx = wave_reduce_max(v);
    float ex = (t < OUT_FEATS) ? expf(logits - mx) : 0.f;
    float s = wave_reduce_sum(ex);
    if (t < OUT_FEATS) out[n * OUT_FEATS + t] = logits - mx - logf(s);
  }
}

extern "C" void kernel_launch(void* const* d_in, const int* in_sizes, int n_in,
                              void* d_out, int out_size, void* d_ws, size_t ws_size,
                              hipStream_t stream) {
  const float* features = (const float*)d_in[0];
  const int* src = (const int*)d_in[1];
  const int* dst = (const int*)d_in[2];
  const float* W1 = (const float*)d_in[3];
  const float* al1 = (const float*)d_in[4];
  const float* ar1 = (const float*)d_in[5];
  const float* W2 = (const float*)d_in[6];
  const float* al2 = (const float*)d_in[7];
  const float* ar2 = (const float*)d_in[8];
  float* out = (float*)d_out;

  char* ws = (char*)d_ws;
  size_t o = 0;
  auto alloc = [&](size_t bytes) {
    void* p = ws + o;
    o = (o + bytes + 255) & ~(size_t)255;
    return p;
  };
  unsigned short* feat1h = (unsigned short*)alloc((size_t)N_NODES * 256 * 2);
  unsigned short* h2h = (unsigned short*)alloc((size_t)N_NODES * 256 * 2);
  float* el1 = (float*)alloc((size_t)N_NODES * 4 * 4);
  float* er1 = (float*)alloc((size_t)N_NODES * 4 * 4);
  unsigned short* feat2ph = (unsigned short*)alloc((size_t)N_NODES * 48 * 2);
  float* el2v = (float*)alloc((size_t)N_NODES * 4);
  float* er2v = (float*)alloc((size_t)N_NODES * 4);
  unsigned short* W1f = (unsigned short*)alloc((size_t)256 * 256 * 2);
  unsigned short* W2f = (unsigned short*)alloc((size_t)256 * 48 * 2);
  float* wa = (float*)alloc(256 * 4);
  float* wb = (float*)alloc(256 * 4);
  int* deg = (int*)alloc((size_t)N_NODES * 4);
  int* cursor = (int*)alloc((size_t)N_NODES * 4);
  int* offsets = (int*)alloc((size_t)(N_NODES + 1) * 4);
  int* src_csr = (int*)alloc((size_t)N_EDGES * 4);

  hipMemsetAsync(deg, 0, (size_t)N_NODES * 4, stream);

  prep_kernel<<<1555, 256, 0, stream>>>(dst, deg, W1, W1f, W2, W2f, al2, ar2, wa, wb);
  gemm1_scan_kernel<<<314, 256, 0, stream>>>(features, W1f, al1, ar1, feat1h, el1, er1, deg,
                                             offsets, cursor);
  fill_kernel<<<(N_EDGES + 255) / 256, 256, 0, stream>>>(src, dst, cursor, src_csr);
  agg1_kernel<<<N_NODES, 256, 0, stream>>>(src_csr, offsets, feat1h, el1, er1, wa, wb, h2h,
                                           el2v, er2v);
  gemm2_kernel<<<(N_NODES + 63) / 64, 256, 0, stream>>>(h2h, W2f, feat2ph);
  agg2_kernel<<<N_NODES, 256, 0, stream>>>(src_csr, offsets, feat2ph, el2v, er2v, out);
}